// Round 7
// baseline (4148.621 us; speedup 1.0000x reference)
//
#include <hip/hip_runtime.h>
#include <hip/hip_bf16.h>

typedef unsigned short u16;
typedef unsigned int   u32;
typedef __attribute__((ext_vector_type(8))) __bf16 bf16x8;
typedef __attribute__((ext_vector_type(4))) float  f32x4;
typedef __attribute__((ext_vector_type(4))) u16    u16x4;

#define SEQ     512
#define DMODEL  768
#define NHEAD   12
#define DHEAD   64
#define FDIM    3072
#define NLAYER  12
#define NROWS   8192   // B*S
#define QKVN    2304   // 3*DMODEL

__device__ __forceinline__ u16 f2bf(float f) {
  union { float f; u32 u; } x; x.f = f;
  u32 r = x.u + 0x7fffu + ((x.u >> 16) & 1u);
  return (u16)(r >> 16);
}

// ---------------- weight convert + transpose: in [K][N] f32 -> out [N][K] bf16 (blockIdx.z = layer)
__global__ __launch_bounds__(256) void k_transpose_cvt(const float* __restrict__ in,
                                                       u16* __restrict__ out, int K, int N,
                                                       size_t istride, size_t ostride) {
  __shared__ float tile[32][33];
  in  += (size_t)blockIdx.z * istride;
  out += (size_t)blockIdx.z * ostride;
  int nb = blockIdx.x * 32, kb = blockIdx.y * 32;
  int tx = threadIdx.x, ty = threadIdx.y;
#pragma unroll
  for (int i = 0; i < 4; i++)
    tile[ty + 8 * i][tx] = in[(size_t)(kb + ty + 8 * i) * N + nb + tx];
  __syncthreads();
#pragma unroll
  for (int i = 0; i < 4; i++)
    out[(size_t)(nb + ty + 8 * i) * K + kb + tx] = f2bf(tile[tx][ty + 8 * i]);
}

// ---------------- embedding gather (f32)
__global__ __launch_bounds__(256) void k_embed(const int* __restrict__ tokens,
                                               const float* __restrict__ emb,
                                               float* __restrict__ x) {
  int idx = blockIdx.x * 256 + threadIdx.x;
  int row = idx / 192, c4 = idx % 192;
  int tok = tokens[row];
  reinterpret_cast<float4*>(x + (size_t)row * DMODEL)[c4] =
      reinterpret_cast<const float4*>(emb + (size_t)tok * DMODEL)[c4];
}

// ---------------- T5 relative position bias LUT: lut[h][rel+511], rel = k - q
__global__ __launch_bounds__(256) void k_biaslut(const float* __restrict__ rel_bias,
                                                 float* __restrict__ lut) {
  int idx = blockIdx.x * 256 + threadIdx.x;   // h*1024 + i
  int h = idx >> 10, i = idx & 1023;
  int rel = i - 511;
  int ret = rel > 0 ? 16 : 0;
  int n = rel < 0 ? -rel : rel;
  int b;
  if (n < 8) {
    b = n;
  } else {
    float r = logf((float)n * 0.125f) / 2.772588722239781f * 8.0f;
    int lg = 8 + (int)r;
    b = lg < 15 ? lg : 15;
  }
  b += ret;
  lut[idx] = rel_bias[b * NHEAD + h];
}

// ---------------- RMSNorm: wave per row, float4 loads, no barrier
template <int BF16OUT>
__global__ __launch_bounds__(256) void k_rmsnorm(const float* __restrict__ x,
                                                 const float* __restrict__ w,
                                                 void* __restrict__ out) {
  int row = blockIdx.x * 4 + (threadIdx.x >> 6);
  int lane = threadIdx.x & 63;
  const float4* xr = reinterpret_cast<const float4*>(x + (size_t)row * DMODEL);
  float4 a = xr[lane], b = xr[lane + 64], c = xr[lane + 128];
  float ss = a.x * a.x + a.y * a.y + a.z * a.z + a.w * a.w
           + b.x * b.x + b.y * b.y + b.z * b.z + b.w * b.w
           + c.x * c.x + c.y * c.y + c.z * c.z + c.w * c.w;
#pragma unroll
  for (int off = 1; off < 64; off <<= 1) ss += __shfl_xor(ss, off);
  float sc = rsqrtf(ss * (1.0f / 768.0f) + 1e-6f);
  const float4* wr = reinterpret_cast<const float4*>(w);
  float4 w0 = wr[lane], w1 = wr[lane + 64], w2 = wr[lane + 128];
  if (BF16OUT) {
    u16x4* o = reinterpret_cast<u16x4*>((u16*)out + (size_t)row * DMODEL);
    u16x4 v0, v1, v2;
    v0[0] = f2bf(a.x * sc * w0.x); v0[1] = f2bf(a.y * sc * w0.y);
    v0[2] = f2bf(a.z * sc * w0.z); v0[3] = f2bf(a.w * sc * w0.w);
    v1[0] = f2bf(b.x * sc * w1.x); v1[1] = f2bf(b.y * sc * w1.y);
    v1[2] = f2bf(b.z * sc * w1.z); v1[3] = f2bf(b.w * sc * w1.w);
    v2[0] = f2bf(c.x * sc * w2.x); v2[1] = f2bf(c.y * sc * w2.y);
    v2[2] = f2bf(c.z * sc * w2.z); v2[3] = f2bf(c.w * sc * w2.w);
    o[lane] = v0; o[lane + 64] = v1; o[lane + 128] = v2;
  } else {
    float4* o = reinterpret_cast<float4*>((float*)out + (size_t)row * DMODEL);
    float4 v0, v1, v2;
    v0.x = a.x * sc * w0.x; v0.y = a.y * sc * w0.y; v0.z = a.z * sc * w0.z; v0.w = a.w * sc * w0.w;
    v1.x = b.x * sc * w1.x; v1.y = b.y * sc * w1.y; v1.z = b.z * sc * w1.z; v1.w = b.w * sc * w1.w;
    v2.x = c.x * sc * w2.x; v2.y = c.y * sc * w2.y; v2.z = c.z * sc * w2.z; v2.w = c.w * sc * w2.w;
    o[lane] = v0; o[lane + 64] = v1; o[lane + 128] = v2;
  }
}

// ---------------- async global->LDS, 16B per lane
__device__ __forceinline__ void gload_lds16(const void* g, void* l) {
  __builtin_amdgcn_global_load_lds((const __attribute__((address_space(1))) void*)g,
                                   (__attribute__((address_space(3))) void*)l, 16, 0, 0);
}

__device__ __forceinline__ bf16x8 rdfrag(const u16* base, int r, int kk, int lh) {
  return *reinterpret_cast<const bf16x8*>(base + r * 64 + (((kk * 4 + lh) ^ (r & 7)) * 8));
}

// ---------------- 256x256 8-wave 8-phase pipelined bf16 GEMM (m201 port), split-K capable.
// C[M,N] = A[M,K(slice)] * Bt[N,K(slice)]^T.  Ksub = K-cols per z-split (blockIdx.z).
// LDS: 2 buf x {A-h0,A-h1,B-h0,B-h1} regions of [128 rows][64 k] bf16 (16KB each) = 128KB.
// Per K-tile: 4 phases x {ds-reads, 1 half-tile stage (2 gloads), bar, lgkm0, 16 MFMA, bar};
// stages: p0/p1 -> A-halves(t+1), p2/p3 -> B-halves(t+2); vmcnt(4) once per tile at p3.
// EPI: 0 = store bf16, 1 = relu -> bf16, 3 = atomicAdd f32 (split-K / residual)
template <int EPI>
__global__ __launch_bounds__(512, 2) void k_gemm(const u16* __restrict__ A, const u16* __restrict__ Bt,
                                                 u16* __restrict__ outb, float* __restrict__ outf,
                                                 int M, int N, int K, int Ksub) {
  __shared__ u16 lds[65536];   // 128 KiB
  const int NT = Ksub >> 6;
  int tid = threadIdx.x;
  int lane = tid & 63, wid = tid >> 6;
  int lr = lane & 15, lh = lane >> 4;
  int wm = wid >> 2, wn = wid & 3;       // 2M x 4N waves; per-wave 128x64 output

  // T1: bijective XCD swizzle (nwg % 8 == 0 for all grids); M-fastest within chunk
  int gx = gridDim.x, gm = gridDim.y;
  int nwg = gx * gm * gridDim.z;
  int linear = (blockIdx.z * gm + blockIdx.y) * gx + blockIdx.x;
  int cpx = nwg >> 3;
  int swz = (linear & 7) * cpx + (linear >> 3);
  int bmi = swz % gm, rest = swz / gm;
  int bni = rest % gx, zi = rest / gx;
  int bm = bmi * 256, bn = bni * 256;
  const u16* Ab = A  + (size_t)bm * K + zi * Ksub;
  const u16* Bb = Bt + (size_t)bn * K + zi * Ksub;

  f32x4 acc[8][4] = {};

  // stage one half-tile region: 128 rows x 64 k, source chunk-swizzled (inverse of read)
  auto STAGE = [&](const u16* mat, int half, int kt, int bufi, int regidx) {
    u16* dst = lds + bufi * 32768 + regidx * 8192;
#pragma unroll
    for (int i = 0; i < 2; i++) {
      int elem = i * 512 + tid;
      int row = elem >> 3, ch = elem & 7;
      int chs = ch ^ (row & 7);
      gload_lds16(mat + (size_t)(half * 128 + row) * K + kt * 64 + chs * 8, dst + elem * 8);
    }
  };

  // prologue: A(0), B(0), B(1)  [12 issues]
  STAGE(Ab, 0, 0, 0, 0); STAGE(Ab, 1, 0, 0, 1);
  STAGE(Bb, 0, 0, 0, 2); STAGE(Bb, 1, 0, 0, 3);
  STAGE(Bb, 0, 1, 1, 2); STAGE(Bb, 1, 1, 1, 3);
  asm volatile("s_waitcnt vmcnt(4)" ::: "memory");
  __builtin_amdgcn_s_barrier();

  int bcol = (wn & 1) * 64;   // column offset inside wave's B-half region

#define LGKM0 asm volatile("s_waitcnt lgkmcnt(0)" ::: "memory"); __builtin_amdgcn_sched_barrier(0)
#define MFMA_Q(MQ, KK)                                                          \
  __builtin_amdgcn_s_setprio(1);                                                \
  _Pragma("unroll") for (int i = 0; i < 4; i++)                                 \
  _Pragma("unroll") for (int n = 0; n < 4; n++)                                 \
    acc[(MQ) * 4 + i][n] =                                                      \
        __builtin_amdgcn_mfma_f32_16x16x32_bf16(af[i], bfr[KK][n], acc[(MQ) * 4 + i][n], 0, 0, 0); \
  __builtin_amdgcn_s_setprio(0);

  for (int t = 0; t < NT; ++t) {
    const u16* bufc = lds + (t & 1) * 32768;
    const u16* curA = bufc + wm * 8192;                  // wave's A-half
    const u16* curB = bufc + 16384 + (wn >> 1) * 8192;   // wave's B-half
    int t1 = (t + 1 < NT) ? t + 1 : 0;                   // wrapped dummies keep vmcnt uniform
    int t2 = (t + 2 < NT) ? t + 2 : t + 2 - NT;
    int b1 = (t + 1) & 1, b2 = t & 1;
    bf16x8 bfr[2][4], af[4];

    // ---- p0: read B(all 8) + A mq0 kk0; stage A-h0(t+1)
#pragma unroll
    for (int n = 0; n < 4; n++) {
      int c = bcol + n * 16 + lr;
      bfr[0][n] = rdfrag(curB, c, 0, lh);
      bfr[1][n] = rdfrag(curB, c, 1, lh);
    }
#pragma unroll
    for (int i = 0; i < 4; i++) af[i] = rdfrag(curA, i * 16 + lr, 0, lh);
    STAGE(Ab, 0, t1, b1, 0);
    __builtin_amdgcn_s_barrier();
    LGKM0;
    MFMA_Q(0, 0)
    __builtin_amdgcn_s_barrier();

    // ---- p1: read A mq0 kk1; stage A-h1(t+1)
#pragma unroll
    for (int i = 0; i < 4; i++) af[i] = rdfrag(curA, i * 16 + lr, 1, lh);
    STAGE(Ab, 1, t1, b1, 1);
    __builtin_amdgcn_s_barrier();
    LGKM0;
    MFMA_Q(0, 1)
    __builtin_amdgcn_s_barrier();

    // ---- p2: read A mq1 kk0; stage B-h0(t+2)
#pragma unroll
    for (int i = 0; i < 4; i++) af[i] = rdfrag(curA, 64 + i * 16 + lr, 0, lh);
    STAGE(Bb, 0, t2, b2, 2);
    __builtin_amdgcn_s_barrier();
    LGKM0;
    MFMA_Q(1, 0)
    __builtin_amdgcn_s_barrier();

    // ---- p3: read A mq1 kk1; stage B-h1(t+2); counted vmcnt (never 0)
#pragma unroll
    for (int i = 0; i < 4; i++) af[i] = rdfrag(curA, 64 + i * 16 + lr, 1, lh);
    STAGE(Bb, 1, t2, b2, 3);
    asm volatile("s_waitcnt vmcnt(4)" ::: "memory");
    __builtin_amdgcn_s_barrier();
    LGKM0;
    MFMA_Q(1, 1)
    __builtin_amdgcn_s_barrier();
  }
#undef MFMA_Q
#undef LGKM0

  // epilogue
#pragma unroll
  for (int mf = 0; mf < 8; mf++)
#pragma unroll
    for (int nf = 0; nf < 4; nf++)
#pragma unroll
      for (int r = 0; r < 4; r++) {
        int row = bm + wm * 128 + mf * 16 + lh * 4 + r;
        int col = bn + wn * 64 + nf * 16 + lr;
        size_t idx = (size_t)row * N + col;
        float v = acc[mf][nf][r];
        if (EPI == 0)      outb[idx] = f2bf(v);
        else if (EPI == 1) outb[idx] = f2bf(v > 0.f ? v : 0.f);
        else               atomicAdd(&outf[idx], v);
      }
}

// ---------------- V transpose per (b,h): qkv V-section [S][64] -> vt[bh][64][S] bf16
__global__ __launch_bounds__(256) void k_vtrans(const u16* __restrict__ qkv, u16* __restrict__ vt) {
  __shared__ u16 t[32][33];
  int bh = blockIdx.z;
  int b = bh / NHEAD, h = bh % NHEAD;
  int d0 = blockIdx.x * 32, s0 = blockIdx.y * 32;
  int tx = threadIdx.x, ty = threadIdx.y;
  const u16* src = qkv + (size_t)(b * SEQ + s0) * QKVN + 2 * DMODEL + h * DHEAD + d0;
#pragma unroll
  for (int i = 0; i < 4; i++)
    t[ty + 8 * i][tx] = src[(size_t)(ty + 8 * i) * QKVN + tx];   // t[s][d]
  __syncthreads();
  u16* dst = vt + ((size_t)bh * DHEAD + d0) * SEQ + s0;
#pragma unroll
  for (int i = 0; i < 4; i++)
    dst[(size_t)(ty + 8 * i) * SEQ + tx] = t[tx][ty + 8 * i];
}

// ---------------- MFMA flash attention: KVBLK=64, dbuf prefetch, counted vmcnt,
// LDS bias LUT, per-lane partial denominator, defer-rescale (THR=8)
__global__ __launch_bounds__(256) void k_attn(const u16* __restrict__ qkv,
                                              const u16* __restrict__ vt,
                                              const float* __restrict__ lutg,
                                              u16* __restrict__ ob) {
  __shared__ __align__(16) float lut[1024];
  __shared__ __align__(16) u16 Ks[2][4096];
  __shared__ __align__(16) u16 Vs[2][4096];
  __shared__ __align__(16) u16 Ps[4][2048];
  int b = blockIdx.x / NHEAD, h = blockIdx.x % NHEAD;
  int qt = blockIdx.y;
  int tid = threadIdx.x;
  int lane = tid & 63, wid = tid >> 6;
  int lr = lane & 15, lh = lane >> 4;
  int q0 = qt * 128 + wid * 32;

  reinterpret_cast<float4*>(lut)[tid] = reinterpret_cast<const float4*>(lutg + h * 1024)[tid];

  bf16x8 aq[2][2];
#pragma unroll
  for (int m = 0; m < 2; m++) {
    const u16* qp = qkv + (size_t)(b * SEQ + q0 + m * 16 + lr) * QKVN + h * DHEAD;
#pragma unroll
    for (int kk = 0; kk < 2; kk++)
      aq[m][kk] = *reinterpret_cast<const bf16x8*>(qp + kk * 32 + lh * 8);
  }

  float mrun[2][4], lpart[2][4];
  f32x4 acc_o[2][4] = {};
#pragma unroll
  for (int m = 0; m < 2; m++)
#pragma unroll
    for (int r = 0; r < 4; r++) { mrun[m][r] = -3.0e38f; lpart[m][r] = 0.f; }

  int srow = tid >> 3, sc8 = tid & 7;
  int scs = (sc8 ^ (srow & 7)) << 3;
  const u16* kbase = qkv + (size_t)(b * SEQ + srow) * QKVN + DMODEL + h * DHEAD + scs;
  const u16* vbase = vt + ((size_t)blockIdx.x * DHEAD + srow) * SEQ + scs;

  auto STAGE = [&](int kt, int bufi) {
    int kv0 = kt << 6;
    gload_lds16(kbase + (size_t)kv0 * QKVN,        &Ks[bufi][tid * 8]);
    gload_lds16(kbase + (size_t)(kv0 + 32) * QKVN, &Ks[bufi][2048 + tid * 8]);
    gload_lds16(vbase + kv0,                       &Vs[bufi][tid * 8]);
    gload_lds16(vbase + 32 * SEQ + kv0,            &Vs[bufi][2048 + tid * 8]);
  };

  STAGE(0, 0);
  asm volatile("s_waitcnt vmcnt(0) lgkmcnt(0)" ::: "memory");
  __builtin_amdgcn_s_barrier();

  int ibase = 511 + lr - q0 - lh * 4;
  u16* pw = Ps[wid];

  for (int kt = 0; kt < 8; kt++) {
    int cb = kt & 1;
    __builtin_amdgcn_s_barrier();
    STAGE((kt + 1) & 7, cb ^ 1);
    asm volatile("s_waitcnt vmcnt(4)" ::: "memory");
    __builtin_amdgcn_s_barrier();

    const u16* KsC = Ks[cb];
    const u16* VsC = Vs[cb];
    int kv0 = kt << 6;

    f32x4 sc[2][4] = {};
#pragma unroll
    for (int kk = 0; kk < 2; kk++) {
      bf16x8 bk[4];
#pragma unroll
      for (int n = 0; n < 4; n++) {
        int row = n * 16 + lr;
        int c = (kk * 4 + lh) ^ (lr & 7);
        bk[n] = *reinterpret_cast<const bf16x8*>(KsC + row * 64 + c * 8);
      }
#pragma unroll
      for (int m = 0; m < 2; m++)
#pragma unroll
        for (int n = 0; n < 4; n++)
          sc[m][n] = __builtin_amdgcn_mfma_f32_16x16x32_bf16(aq[m][kk], bk[n], sc[m][n], 0, 0, 0);
    }

    int pred = 1;
    float vmax[2][4];
#pragma unroll
    for (int m = 0; m < 2; m++)
#pragma unroll
      for (int r = 0; r < 4; r++) {
        int ib = ibase + kv0 - m * 16 - r;
#pragma unroll
        for (int n = 0; n < 4; n++)
          sc[m][n][r] += lut[ib + n * 16];
        float v = fmaxf(fmaxf(sc[m][0][r], sc[m][1][r]), fmaxf(sc[m][2][r], sc[m][3][r]));
        v = fmaxf(v, __shfl_xor(v, 1));
        v = fmaxf(v, __shfl_xor(v, 2));
        v = fmaxf(v, __shfl_xor(v, 4));
        v = fmaxf(v, __shfl_xor(v, 8));
        vmax[m][r] = v;
        pred = pred && (v <= mrun[m][r] + 8.0f);
      }
    if (!__all(pred)) {
#pragma unroll
      for (int m = 0; m < 2; m++)
#pragma unroll
        for (int r = 0; r < 4; r++) {
          float mo = mrun[m][r];
          float mn = fmaxf(mo, vmax[m][r]);
          float corr = __expf(mo - mn);
          mrun[m][r] = mn;
          lpart[m][r] *= corr;
#pragma unroll
          for (int n = 0; n < 4; n++) acc_o[m][n][r] *= corr;
        }
    }
#pragma unroll
    for (int m = 0; m < 2; m++)
#pragma unroll
      for (int r = 0; r < 4; r++) {
        float mm = mrun[m][r];
        int prow = m * 16 + lh * 4 + r;
        int pbse = prow * 64;
        int sw = prow & 7;
        float lp = lpart[m][r];
#pragma unroll
        for (int n = 0; n < 4; n++) {
          float pv = __expf(sc[m][n][r] - mm);
          lp += pv;
          pw[pbse + ((((n << 1) | (lr >> 3)) ^ sw) << 3) + (lr & 7)] = f2bf(pv);
        }
        lpart[m][r] = lp;
      }

    asm volatile("s_waitcnt lgkmcnt(0)" ::: "memory");
    __builtin_amdgcn_sched_barrier(0);
#pragma unroll
    for (int kk = 0; kk < 2; kk++) {
      bf16x8 bvv[4], ap[2];
#pragma unroll
      for (int n = 0; n < 4; n++) {
        int row = n * 16 + lr;
        int c = (kk * 4 + lh) ^ (lr & 7);
        bvv[n] = *reinterpret_cast<const bf16x8*>(VsC + row * 64 + c * 8);
      }
#pragma unroll
      for (int m = 0; m < 2; m++) {
        int row = m * 16 + lr;
        int c = (kk * 4 + lh) ^ (lr & 7);
        ap[m] = *reinterpret_cast<const bf16x8*>(pw + row * 64 + c * 8);
      }
#pragma unroll
      for (int m = 0; m < 2; m++)
#pragma unroll
        for (int n = 0; n < 4; n++)
          acc_o[m][n] = __builtin_amdgcn_mfma_f32_16x16x32_bf16(ap[m], bvv[n], acc_o[m][n], 0, 0, 0);
    }
  }

#pragma unroll
  for (int m = 0; m < 2; m++)
#pragma unroll
    for (int r = 0; r < 4; r++) {
      float l = lpart[m][r];
      l += __shfl_xor(l, 1);
      l += __shfl_xor(l, 2);
      l += __shfl_xor(l, 4);
      l += __shfl_xor(l, 8);
      float inv = 1.f / l;
      size_t orow = (size_t)(b * SEQ + q0 + m * 16 + lh * 4 + r);
#pragma unroll
      for (int n = 0; n < 4; n++)
        ob[orow * DMODEL + h * DHEAD + n * 16 + lr] = f2bf(acc_o[m][n][r] * inv);
    }
}

extern "C" void kernel_launch(void* const* d_in, const int* in_sizes, int n_in,
                              void* d_out, int out_size, void* d_ws, size_t ws_size,
                              hipStream_t stream) {
  const int*   tokens = (const int*)  d_in[0];
  const float* emb    = (const float*)d_in[1];
  const float* relb   = (const float*)d_in[2];
  const float* ln1w   = (const float*)d_in[3];
  const float* wq     = (const float*)d_in[4];
  const float* wk     = (const float*)d_in[5];
  const float* wv     = (const float*)d_in[6];
  const float* wo     = (const float*)d_in[7];
  const float* ln2w   = (const float*)d_in[8];
  const float* w1     = (const float*)d_in[9];
  const float* w2     = (const float*)d_in[10];
  const float* lnfw   = (const float*)d_in[11];
  float* out = (float*)d_out;

  char* p = (char*)d_ws;
  auto carve = [&](size_t bytes) { char* r = p; p += (bytes + 255) & ~(size_t)255; return r; };
  const size_t DD = (size_t)DMODEL * DMODEL, DF = (size_t)DMODEL * FDIM;

  u16*   wqkv_t = (u16*)carve(NLAYER * 3 * DD * 2);
  u16*   wo_t   = (u16*)carve(NLAYER * DD * 2);
  u16*   w1_t   = (u16*)carve(NLAYER * DF * 2);
  u16*   w2_t   = (u16*)carve(NLAYER * DF * 2);
  float* x      = (float*)carve((size_t)NROWS * DMODEL * 4);
  u16*   hbuf   = (u16*)carve((size_t)NROWS * DMODEL * 2);
  u16*   qkvbuf = (u16*)carve((size_t)NROWS * QKVN * 2);
  u16*   abuf   = (u16*)carve((size_t)NROWS * DMODEL * 2);
  u16*   fbuf   = (u16*)carve((size_t)NROWS * FDIM * 2);
  float* lutbuf = (float*)carve((size_t)NHEAD * 1024 * 4);
  u16*   vtbuf  = fbuf;   // overlay: vt dead before ffn1 writes fbuf

  dim3 tb(32, 8);
  k_transpose_cvt<<<dim3(24, 24, NLAYER), tb, 0, stream>>>(wq, wqkv_t,          DMODEL, DMODEL, DD, 3 * DD);
  k_transpose_cvt<<<dim3(24, 24, NLAYER), tb, 0, stream>>>(wk, wqkv_t + DD,     DMODEL, DMODEL, DD, 3 * DD);
  k_transpose_cvt<<<dim3(24, 24, NLAYER), tb, 0, stream>>>(wv, wqkv_t + 2 * DD, DMODEL, DMODEL, DD, 3 * DD);
  k_transpose_cvt<<<dim3(24, 24, NLAYER), tb, 0, stream>>>(wo, wo_t,            DMODEL, DMODEL, DD, DD);
  k_transpose_cvt<<<dim3(96, 24, NLAYER), tb, 0, stream>>>(w1, w1_t,            DMODEL, FDIM,   DF, DF);
  k_transpose_cvt<<<dim3(24, 96, NLAYER), tb, 0, stream>>>(w2, w2_t,            FDIM, DMODEL,   DF, DF);

  k_embed<<<NROWS * 192 / 256, 256, 0, stream>>>(tokens, emb, x);
  k_biaslut<<<48, 256, 0, stream>>>(relb, lutbuf);

  for (int i = 0; i < NLAYER; i++) {
    k_rmsnorm<1><<<NROWS / 4, 256, 0, stream>>>(x, ln1w + i * DMODEL, hbuf);
    // QKV: [8192 x 2304] = hbuf * Wqkv^T
    k_gemm<0><<<dim3(9, 32, 1), 512, 0, stream>>>(hbuf, wqkv_t + (size_t)i * 3 * DD, qkvbuf, nullptr,
                                                  NROWS, QKVN, DMODEL, DMODEL);
    k_vtrans<<<dim3(2, 16, 192), tb, 0, stream>>>(qkvbuf, vtbuf);
    k_attn<<<dim3(192, 4), 256, 0, stream>>>(qkvbuf, vtbuf, lutbuf, abuf);
    // WO: split-K x2, atomic accumulate into residual x
    k_gemm<3><<<dim3(3, 32, 2), 512, 0, stream>>>(abuf, wo_t + (size_t)i * DD, nullptr, x,
                                                  NROWS, DMODEL, DMODEL, DMODEL / 2);
    k_rmsnorm<1><<<NROWS / 4, 256, 0, stream>>>(x, ln2w + i * DMODEL, hbuf);
    // FFN1: relu epilogue
    k_gemm<1><<<dim3(12, 32, 1), 512, 0, stream>>>(hbuf, w1_t + (size_t)i * DF, fbuf, nullptr,
                                                   NROWS, FDIM, DMODEL, DMODEL);
    // FFN2: split-K x4, atomic accumulate into residual x
    k_gemm<3><<<dim3(3, 32, 4), 512, 0, stream>>>(fbuf, w2_t + (size_t)i * DF, nullptr, x,
                                                  NROWS, DMODEL, FDIM, FDIM / 4);
  }
  k_rmsnorm<0><<<NROWS / 4, 256, 0, stream>>>(x, lnfw, out);
}

// Round 8
// 3745.399 us; speedup vs baseline: 1.1077x; 1.1077x over previous
//
#include <hip/hip_runtime.h>
#include <hip/hip_bf16.h>

typedef unsigned short u16;
typedef unsigned int   u32;
typedef __attribute__((ext_vector_type(8))) __bf16 bf16x8;
typedef __attribute__((ext_vector_type(4))) float  f32x4;
typedef __attribute__((ext_vector_type(4))) u16    u16x4;

#define SEQ     512
#define DMODEL  768
#define NHEAD   12
#define DHEAD   64
#define FDIM    3072
#define NLAYER  12
#define NROWS   8192   // B*S
#define QKVN    2304   // 3*DMODEL

__device__ __forceinline__ u16 f2bf(float f) {
  union { float f; u32 u; } x; x.f = f;
  u32 r = x.u + 0x7fffu + ((x.u >> 16) & 1u);
  return (u16)(r >> 16);
}

// ---------------- weight convert + transpose: in [K][N] f32 -> out [N][K] bf16 (blockIdx.z = layer)
__global__ __launch_bounds__(256) void k_transpose_cvt(const float* __restrict__ in,
                                                       u16* __restrict__ out, int K, int N,
                                                       size_t istride, size_t ostride) {
  __shared__ float tile[32][33];
  in  += (size_t)blockIdx.z * istride;
  out += (size_t)blockIdx.z * ostride;
  int nb = blockIdx.x * 32, kb = blockIdx.y * 32;
  int tx = threadIdx.x, ty = threadIdx.y;
#pragma unroll
  for (int i = 0; i < 4; i++)
    tile[ty + 8 * i][tx] = in[(size_t)(kb + ty + 8 * i) * N + nb + tx];
  __syncthreads();
#pragma unroll
  for (int i = 0; i < 4; i++)
    out[(size_t)(nb + ty + 8 * i) * K + kb + tx] = f2bf(tile[tx][ty + 8 * i]);
}

// ---------------- embedding gather (f32)
__global__ __launch_bounds__(256) void k_embed(const int* __restrict__ tokens,
                                               const float* __restrict__ emb,
                                               float* __restrict__ x) {
  int idx = blockIdx.x * 256 + threadIdx.x;
  int row = idx / 192, c4 = idx % 192;
  int tok = tokens[row];
  reinterpret_cast<float4*>(x + (size_t)row * DMODEL)[c4] =
      reinterpret_cast<const float4*>(emb + (size_t)tok * DMODEL)[c4];
}

// ---------------- T5 relative position bias LUT: lut[h][rel+511], rel = k - q
__global__ __launch_bounds__(256) void k_biaslut(const float* __restrict__ rel_bias,
                                                 float* __restrict__ lut) {
  int idx = blockIdx.x * 256 + threadIdx.x;   // h*1024 + i
  int h = idx >> 10, i = idx & 1023;
  int rel = i - 511;
  int ret = rel > 0 ? 16 : 0;
  int n = rel < 0 ? -rel : rel;
  int b;
  if (n < 8) {
    b = n;
  } else {
    float r = logf((float)n * 0.125f) / 2.772588722239781f * 8.0f;
    int lg = 8 + (int)r;
    b = lg < 15 ? lg : 15;
  }
  b += ret;
  lut[idx] = rel_bias[b * NHEAD + h];
}

// ---------------- RMSNorm: wave per row, float4 loads, no barrier
template <int BF16OUT>
__global__ __launch_bounds__(256) void k_rmsnorm(const float* __restrict__ x,
                                                 const float* __restrict__ w,
                                                 void* __restrict__ out) {
  int row = blockIdx.x * 4 + (threadIdx.x >> 6);
  int lane = threadIdx.x & 63;
  const float4* xr = reinterpret_cast<const float4*>(x + (size_t)row * DMODEL);
  float4 a = xr[lane], b = xr[lane + 64], c = xr[lane + 128];
  float ss = a.x * a.x + a.y * a.y + a.z * a.z + a.w * a.w
           + b.x * b.x + b.y * b.y + b.z * b.z + b.w * b.w
           + c.x * c.x + c.y * c.y + c.z * c.z + c.w * c.w;
#pragma unroll
  for (int off = 1; off < 64; off <<= 1) ss += __shfl_xor(ss, off);
  float sc = rsqrtf(ss * (1.0f / 768.0f) + 1e-6f);
  const float4* wr = reinterpret_cast<const float4*>(w);
  float4 w0 = wr[lane], w1 = wr[lane + 64], w2 = wr[lane + 128];
  if (BF16OUT) {
    u16x4* o = reinterpret_cast<u16x4*>((u16*)out + (size_t)row * DMODEL);
    u16x4 v0, v1, v2;
    v0[0] = f2bf(a.x * sc * w0.x); v0[1] = f2bf(a.y * sc * w0.y);
    v0[2] = f2bf(a.z * sc * w0.z); v0[3] = f2bf(a.w * sc * w0.w);
    v1[0] = f2bf(b.x * sc * w1.x); v1[1] = f2bf(b.y * sc * w1.y);
    v1[2] = f2bf(b.z * sc * w1.z); v1[3] = f2bf(b.w * sc * w1.w);
    v2[0] = f2bf(c.x * sc * w2.x); v2[1] = f2bf(c.y * sc * w2.y);
    v2[2] = f2bf(c.z * sc * w2.z); v2[3] = f2bf(c.w * sc * w2.w);
    o[lane] = v0; o[lane + 64] = v1; o[lane + 128] = v2;
  } else {
    float4* o = reinterpret_cast<float4*>((float*)out + (size_t)row * DMODEL);
    float4 v0, v1, v2;
    v0.x = a.x * sc * w0.x; v0.y = a.y * sc * w0.y; v0.z = a.z * sc * w0.z; v0.w = a.w * sc * w0.w;
    v1.x = b.x * sc * w1.x; v1.y = b.y * sc * w1.y; v1.z = b.z * sc * w1.z; v1.w = b.w * sc * w1.w;
    v2.x = c.x * sc * w2.x; v2.y = c.y * sc * w2.y; v2.z = c.z * sc * w2.z; v2.w = c.w * sc * w2.w;
    o[lane] = v0; o[lane + 64] = v1; o[lane + 128] = v2;
  }
}

// ---------------- async global->LDS, 16B per lane
__device__ __forceinline__ void gload_lds16(const void* g, void* l) {
  __builtin_amdgcn_global_load_lds((const __attribute__((address_space(1))) void*)g,
                                   (__attribute__((address_space(3))) void*)l, 16, 0, 0);
}

// ---------------- 128x128 4-wave BK=32 triple-buffered pipelined bf16 GEMM: C = A[M,K]*Bt[N,K]^T
// 3 blocks/CU (48KB LDS). Per wave 64x64 (4M x 4N frags). Per K-tile: 8 ds_read_b128,
// 4 stage issues (tile t+2), one barrier pair, 16 MFMA, counted vmcnt(4) (never 0).
// Buffer (u16): A[128][32] at 0 (4096), B[128][32] at 4096. Buffer = 8192 u16 = 16KB.
// EPI: 0 = store bf16, 1 = relu -> bf16, 2 = += f32 (residual, single writer)
template <int EPI>
__global__ __launch_bounds__(256, 3) void k_gemm(const u16* __restrict__ A, const u16* __restrict__ Bt,
                                                 u16* __restrict__ outb, float* __restrict__ outf,
                                                 int M, int N, int K) {
  __shared__ u16 lds[3 * 8192];   // 48 KiB
  const int NT = K >> 5;
  int tid = threadIdx.x;
  int lane = tid & 63, wid = tid >> 6;
  int lr = lane & 15, lh = lane >> 4;
  int wm = wid >> 1, wn = wid & 1;   // 2M x 2N waves, 64x64 per wave

  // T1: bijective XCD swizzle (all grids %8==0); M-fastest within chunk (weights L2-hot)
  int gx = gridDim.x, gm = gridDim.y;
  int nwg = gx * gm;
  int linear = blockIdx.y * gx + blockIdx.x;
  int cpx = nwg >> 3;
  int swz = (linear & 7) * cpx + (linear >> 3);
  int bm = (swz % gm) * 128;
  int bn = (swz / gm) * 128;

  const u16* Ab = A  + (size_t)bm * K;
  const u16* Bb = Bt + (size_t)bn * K;

  f32x4 acc[4][4] = {};

  // stage tile kt into buf: 128 rows x 32 k each of A and B; source chunk pre-swizzled
  auto STAGE = [&](int kt, u16* buf) {
#pragma unroll
    for (int i = 0; i < 2; i++) {
      int elem = i * 256 + tid;            // 0..511
      int row = elem >> 2, pc = elem & 3;
      int chs = pc ^ (row & 3);            // inverse of read swizzle
      gload_lds16(Ab + (size_t)row * K + kt * 32 + chs * 8, buf + elem * 8);
      gload_lds16(Bb + (size_t)row * K + kt * 32 + chs * 8, buf + 4096 + elem * 8);
    }
  };

  // prologue: tiles 0,1
  STAGE(0, lds);
  STAGE(1, lds + 8192);
  asm volatile("s_waitcnt vmcnt(4)" ::: "memory");   // tile0 landed; tile1 in flight
  __builtin_amdgcn_s_barrier();

  int cs = 0;
  for (int t = 0; t < NT; ++t) {
    const u16* cur = lds + cs * 8192;
    int ds = cs + 2; if (ds >= 3) ds -= 3;
    int t2 = t + 2; if (t2 >= NT) t2 -= NT;   // wrapped dummy keeps vmcnt uniform

    bf16x8 af[4], bfr[4];
#pragma unroll
    for (int i = 0; i < 4; i++) {
      int r = wm * 64 + i * 16 + lr;
      af[i] = *reinterpret_cast<const bf16x8*>(cur + r * 32 + ((lh ^ (r & 3)) * 8));
    }
#pragma unroll
    for (int n = 0; n < 4; n++) {
      int r = wn * 64 + n * 16 + lr;
      bfr[n] = *reinterpret_cast<const bf16x8*>(cur + 4096 + r * 32 + ((lh ^ (r & 3)) * 8));
    }
    STAGE(t2, lds + ds * 8192);
    __builtin_amdgcn_s_barrier();
    asm volatile("s_waitcnt lgkmcnt(0)" ::: "memory");
    __builtin_amdgcn_sched_barrier(0);
    __builtin_amdgcn_s_setprio(1);
#pragma unroll
    for (int i = 0; i < 4; i++)
#pragma unroll
      for (int n = 0; n < 4; n++)
        acc[i][n] = __builtin_amdgcn_mfma_f32_16x16x32_bf16(af[i], bfr[n], acc[i][n], 0, 0, 0);
    __builtin_amdgcn_s_setprio(0);
    asm volatile("s_waitcnt vmcnt(4)" ::: "memory");   // t+1's loads done; t+2's in flight
    __builtin_amdgcn_s_barrier();
    cs += 1; if (cs >= 3) cs -= 3;
  }

  // epilogue
#pragma unroll
  for (int i = 0; i < 4; i++)
#pragma unroll
    for (int n = 0; n < 4; n++)
#pragma unroll
      for (int r = 0; r < 4; r++) {
        int row = bm + wm * 64 + i * 16 + lh * 4 + r;
        int col = bn + wn * 64 + n * 16 + lr;
        size_t idx = (size_t)row * N + col;
        float v = acc[i][n][r];
        if (EPI == 0)      outb[idx] = f2bf(v);
        else if (EPI == 1) outb[idx] = f2bf(v > 0.f ? v : 0.f);
        else               outf[idx] += v;
      }
}

// ---------------- V transpose per (b,h): qkv V-section [S][64] -> vt[bh][64][S] bf16
__global__ __launch_bounds__(256) void k_vtrans(const u16* __restrict__ qkv, u16* __restrict__ vt) {
  __shared__ u16 t[32][33];
  int bh = blockIdx.z;
  int b = bh / NHEAD, h = bh % NHEAD;
  int d0 = blockIdx.x * 32, s0 = blockIdx.y * 32;
  int tx = threadIdx.x, ty = threadIdx.y;
  const u16* src = qkv + (size_t)(b * SEQ + s0) * QKVN + 2 * DMODEL + h * DHEAD + d0;
#pragma unroll
  for (int i = 0; i < 4; i++)
    t[ty + 8 * i][tx] = src[(size_t)(ty + 8 * i) * QKVN + tx];   // t[s][d]
  __syncthreads();
  u16* dst = vt + ((size_t)bh * DHEAD + d0) * SEQ + s0;
#pragma unroll
  for (int i = 0; i < 4; i++)
    dst[(size_t)(ty + 8 * i) * SEQ + tx] = t[tx][ty + 8 * i];
}

// ---------------- MFMA flash attention: KVBLK=64, dbuf prefetch, counted vmcnt,
// LDS bias LUT, per-lane partial denominator, defer-rescale (THR=8)
__global__ __launch_bounds__(256) void k_attn(const u16* __restrict__ qkv,
                                              const u16* __restrict__ vt,
                                              const float* __restrict__ lutg,
                                              u16* __restrict__ ob) {
  __shared__ __align__(16) float lut[1024];
  __shared__ __align__(16) u16 Ks[2][4096];
  __shared__ __align__(16) u16 Vs[2][4096];
  __shared__ __align__(16) u16 Ps[4][2048];
  int b = blockIdx.x / NHEAD, h = blockIdx.x % NHEAD;
  int qt = blockIdx.y;
  int tid = threadIdx.x;
  int lane = tid & 63, wid = tid >> 6;
  int lr = lane & 15, lh = lane >> 4;
  int q0 = qt * 128 + wid * 32;

  reinterpret_cast<float4*>(lut)[tid] = reinterpret_cast<const float4*>(lutg + h * 1024)[tid];

  bf16x8 aq[2][2];
#pragma unroll
  for (int m = 0; m < 2; m++) {
    const u16* qp = qkv + (size_t)(b * SEQ + q0 + m * 16 + lr) * QKVN + h * DHEAD;
#pragma unroll
    for (int kk = 0; kk < 2; kk++)
      aq[m][kk] = *reinterpret_cast<const bf16x8*>(qp + kk * 32 + lh * 8);
  }

  float mrun[2][4], lpart[2][4];
  f32x4 acc_o[2][4] = {};
#pragma unroll
  for (int m = 0; m < 2; m++)
#pragma unroll
    for (int r = 0; r < 4; r++) { mrun[m][r] = -3.0e38f; lpart[m][r] = 0.f; }

  int srow = tid >> 3, sc8 = tid & 7;
  int scs = (sc8 ^ (srow & 7)) << 3;
  const u16* kbase = qkv + (size_t)(b * SEQ + srow) * QKVN + DMODEL + h * DHEAD + scs;
  const u16* vbase = vt + ((size_t)blockIdx.x * DHEAD + srow) * SEQ + scs;

  auto STAGE = [&](int kt, int bufi) {
    int kv0 = kt << 6;
    gload_lds16(kbase + (size_t)kv0 * QKVN,        &Ks[bufi][tid * 8]);
    gload_lds16(kbase + (size_t)(kv0 + 32) * QKVN, &Ks[bufi][2048 + tid * 8]);
    gload_lds16(vbase + kv0,                       &Vs[bufi][tid * 8]);
    gload_lds16(vbase + 32 * SEQ + kv0,            &Vs[bufi][2048 + tid * 8]);
  };

  STAGE(0, 0);
  asm volatile("s_waitcnt vmcnt(0) lgkmcnt(0)" ::: "memory");
  __builtin_amdgcn_s_barrier();

  int ibase = 511 + lr - q0 - lh * 4;
  u16* pw = Ps[wid];

  for (int kt = 0; kt < 8; kt++) {
    int cb = kt & 1;
    __builtin_amdgcn_s_barrier();
    STAGE((kt + 1) & 7, cb ^ 1);
    asm volatile("s_waitcnt vmcnt(4)" ::: "memory");
    __builtin_amdgcn_s_barrier();

    const u16* KsC = Ks[cb];
    const u16* VsC = Vs[cb];
    int kv0 = kt << 6;

    f32x4 sc[2][4] = {};
#pragma unroll
    for (int kk = 0; kk < 2; kk++) {
      bf16x8 bk[4];
#pragma unroll
      for (int n = 0; n < 4; n++) {
        int row = n * 16 + lr;
        int c = (kk * 4 + lh) ^ (lr & 7);
        bk[n] = *reinterpret_cast<const bf16x8*>(KsC + row * 64 + c * 8);
      }
#pragma unroll
      for (int m = 0; m < 2; m++)
#pragma unroll
        for (int n = 0; n < 4; n++)
          sc[m][n] = __builtin_amdgcn_mfma_f32_16x16x32_bf16(aq[m][kk], bk[n], sc[m][n], 0, 0, 0);
    }

    int pred = 1;
    float vmax[2][4];
#pragma unroll
    for (int m = 0; m < 2; m++)
#pragma unroll
      for (int r = 0; r < 4; r++) {
        int ib = ibase + kv0 - m * 16 - r;
#pragma unroll
        for (int n = 0; n < 4; n++)
          sc[m][n][r] += lut[ib + n * 16];
        float v = fmaxf(fmaxf(sc[m][0][r], sc[m][1][r]), fmaxf(sc[m][2][r], sc[m][3][r]));
        v = fmaxf(v, __shfl_xor(v, 1));
        v = fmaxf(v, __shfl_xor(v, 2));
        v = fmaxf(v, __shfl_xor(v, 4));
        v = fmaxf(v, __shfl_xor(v, 8));
        vmax[m][r] = v;
        pred = pred && (v <= mrun[m][r] + 8.0f);
      }
    if (!__all(pred)) {
#pragma unroll
      for (int m = 0; m < 2; m++)
#pragma unroll
        for (int r = 0; r < 4; r++) {
          float mo = mrun[m][r];
          float mn = fmaxf(mo, vmax[m][r]);
          float corr = __expf(mo - mn);
          mrun[m][r] = mn;
          lpart[m][r] *= corr;
#pragma unroll
          for (int n = 0; n < 4; n++) acc_o[m][n][r] *= corr;
        }
    }
#pragma unroll
    for (int m = 0; m < 2; m++)
#pragma unroll
      for (int r = 0; r < 4; r++) {
        float mm = mrun[m][r];
        int prow = m * 16 + lh * 4 + r;
        int pbse = prow * 64;
        int sw = prow & 7;
        float lp = lpart[m][r];
#pragma unroll
        for (int n = 0; n < 4; n++) {
          float pv = __expf(sc[m][n][r] - mm);
          lp += pv;
          pw[pbse + ((((n << 1) | (lr >> 3)) ^ sw) << 3) + (lr & 7)] = f2bf(pv);
        }
        lpart[m][r] = lp;
      }

    asm volatile("s_waitcnt lgkmcnt(0)" ::: "memory");
    __builtin_amdgcn_sched_barrier(0);
#pragma unroll
    for (int kk = 0; kk < 2; kk++) {
      bf16x8 bvv[4], ap[2];
#pragma unroll
      for (int n = 0; n < 4; n++) {
        int row = n * 16 + lr;
        int c = (kk * 4 + lh) ^ (lr & 7);
        bvv[n] = *reinterpret_cast<const bf16x8*>(VsC + row * 64 + c * 8);
      }
#pragma unroll
      for (int m = 0; m < 2; m++) {
        int row = m * 16 + lr;
        int c = (kk * 4 + lh) ^ (lr & 7);
        ap[m] = *reinterpret_cast<const bf16x8*>(pw + row * 64 + c * 8);
      }
#pragma unroll
      for (int m = 0; m < 2; m++)
#pragma unroll
        for (int n = 0; n < 4; n++)
          acc_o[m][n] = __builtin_amdgcn_mfma_f32_16x16x32_bf16(ap[m], bvv[n], acc_o[m][n], 0, 0, 0);
    }
  }

#pragma unroll
  for (int m = 0; m < 2; m++)
#pragma unroll
    for (int r = 0; r < 4; r++) {
      float l = lpart[m][r];
      l += __shfl_xor(l, 1);
      l += __shfl_xor(l, 2);
      l += __shfl_xor(l, 4);
      l += __shfl_xor(l, 8);
      float inv = 1.f / l;
      size_t orow = (size_t)(b * SEQ + q0 + m * 16 + lh * 4 + r);
#pragma unroll
      for (int n = 0; n < 4; n++)
        ob[orow * DMODEL + h * DHEAD + n * 16 + lr] = f2bf(acc_o[m][n][r] * inv);
    }
}

extern "C" void kernel_launch(void* const* d_in, const int* in_sizes, int n_in,
                              void* d_out, int out_size, void* d_ws, size_t ws_size,
                              hipStream_t stream) {
  const int*   tokens = (const int*)  d_in[0];
  const float* emb    = (const float*)d_in[1];
  const float* relb   = (const float*)d_in[2];
  const float* ln1w   = (const float*)d_in[3];
  const float* wq     = (const float*)d_in[4];
  const float* wk     = (const float*)d_in[5];
  const float* wv     = (const float*)d_in[6];
  const float* wo     = (const float*)d_in[7];
  const float* ln2w   = (const float*)d_in[8];
  const float* w1     = (const float*)d_in[9];
  const float* w2     = (const float*)d_in[10];
  const float* lnfw   = (const float*)d_in[11];
  float* out = (float*)d_out;

  char* p = (char*)d_ws;
  auto carve = [&](size_t bytes) { char* r = p; p += (bytes + 255) & ~(size_t)255; return r; };
  const size_t DD = (size_t)DMODEL * DMODEL, DF = (size_t)DMODEL * FDIM;

  u16*   wqkv_t = (u16*)carve(NLAYER * 3 * DD * 2);
  u16*   wo_t   = (u16*)carve(NLAYER * DD * 2);
  u16*   w1_t   = (u16*)carve(NLAYER * DF * 2);
  u16*   w2_t   = (u16*)carve(NLAYER * DF * 2);
  float* x      = (float*)carve((size_t)NROWS * DMODEL * 4);
  u16*   hbuf   = (u16*)carve((size_t)NROWS * DMODEL * 2);
  u16*   qkvbuf = (u16*)carve((size_t)NROWS * QKVN * 2);
  u16*   abuf   = (u16*)carve((size_t)NROWS * DMODEL * 2);
  u16*   fbuf   = (u16*)carve((size_t)NROWS * FDIM * 2);
  float* lutbuf = (float*)carve((size_t)NHEAD * 1024 * 4);
  u16*   vtbuf  = fbuf;   // overlay: vt dead before ffn1 writes fbuf

  dim3 tb(32, 8);
  k_transpose_cvt<<<dim3(24, 24, NLAYER), tb, 0, stream>>>(wq, wqkv_t,          DMODEL, DMODEL, DD, 3 * DD);
  k_transpose_cvt<<<dim3(24, 24, NLAYER), tb, 0, stream>>>(wk, wqkv_t + DD,     DMODEL, DMODEL, DD, 3 * DD);
  k_transpose_cvt<<<dim3(24, 24, NLAYER), tb, 0, stream>>>(wv, wqkv_t + 2 * DD, DMODEL, DMODEL, DD, 3 * DD);
  k_transpose_cvt<<<dim3(24, 24, NLAYER), tb, 0, stream>>>(wo, wo_t,            DMODEL, DMODEL, DD, DD);
  k_transpose_cvt<<<dim3(96, 24, NLAYER), tb, 0, stream>>>(w1, w1_t,            DMODEL, FDIM,   DF, DF);
  k_transpose_cvt<<<dim3(24, 96, NLAYER), tb, 0, stream>>>(w2, w2_t,            FDIM, DMODEL,   DF, DF);

  k_embed<<<NROWS * 192 / 256, 256, 0, stream>>>(tokens, emb, x);
  k_biaslut<<<48, 256, 0, stream>>>(relb, lutbuf);

  for (int i = 0; i < NLAYER; i++) {
    k_rmsnorm<1><<<NROWS / 4, 256, 0, stream>>>(x, ln1w + i * DMODEL, hbuf);
    k_gemm<0><<<dim3(18, 64), 256, 0, stream>>>(hbuf, wqkv_t + (size_t)i * 3 * DD, qkvbuf, nullptr,
                                                NROWS, QKVN, DMODEL);
    k_vtrans<<<dim3(2, 16, 192), tb, 0, stream>>>(qkvbuf, vtbuf);
    k_attn<<<dim3(192, 4), 256, 0, stream>>>(qkvbuf, vtbuf, lutbuf, abuf);
    k_gemm<2><<<dim3(6, 64),  256, 0, stream>>>(abuf, wo_t + (size_t)i * DD, nullptr, x,
                                                NROWS, DMODEL, DMODEL);
    k_rmsnorm<1><<<NROWS / 4, 256, 0, stream>>>(x, ln2w + i * DMODEL, hbuf);
    k_gemm<1><<<dim3(24, 64), 256, 0, stream>>>(hbuf, w1_t + (size_t)i * DF, fbuf, nullptr,
                                                NROWS, FDIM, DMODEL);
    k_gemm<2><<<dim3(6, 64),  256, 0, stream>>>(fbuf, w2_t + (size_t)i * DF, nullptr, x,
                                                NROWS, DMODEL, FDIM);
  }
  k_rmsnorm<0><<<NROWS / 4, 256, 0, stream>>>(x, lnfw, out);
}

// Round 9
// 3273.040 us; speedup vs baseline: 1.2675x; 1.1443x over previous
//
#include <hip/hip_runtime.h>
#include <hip/hip_bf16.h>

typedef unsigned short u16;
typedef unsigned int   u32;
typedef __attribute__((ext_vector_type(8))) __bf16 bf16x8;
typedef __attribute__((ext_vector_type(4))) float  f32x4;
typedef __attribute__((ext_vector_type(4))) u16    u16x4;

#define SEQ     512
#define DMODEL  768
#define NHEAD   12
#define DHEAD   64
#define FDIM    3072
#define NLAYER  12
#define NROWS   8192   // B*S
#define QKVN    2304   // 3*DMODEL

__device__ __forceinline__ u16 f2bf(float f) {
  union { float f; u32 u; } x; x.f = f;
  u32 r = x.u + 0x7fffu + ((x.u >> 16) & 1u);
  return (u16)(r >> 16);
}

// ---------------- weight convert + transpose: in [K][N] f32 -> out [N][K] bf16 (blockIdx.z = layer)
__global__ __launch_bounds__(256) void k_transpose_cvt(const float* __restrict__ in,
                                                       u16* __restrict__ out, int K, int N,
                                                       size_t istride, size_t ostride) {
  __shared__ float tile[32][33];
  in  += (size_t)blockIdx.z * istride;
  out += (size_t)blockIdx.z * ostride;
  int nb = blockIdx.x * 32, kb = blockIdx.y * 32;
  int tx = threadIdx.x, ty = threadIdx.y;
#pragma unroll
  for (int i = 0; i < 4; i++)
    tile[ty + 8 * i][tx] = in[(size_t)(kb + ty + 8 * i) * N + nb + tx];
  __syncthreads();
#pragma unroll
  for (int i = 0; i < 4; i++)
    out[(size_t)(nb + ty + 8 * i) * K + kb + tx] = f2bf(tile[tx][ty + 8 * i]);
}

// ---------------- embedding gather (f32)
__global__ __launch_bounds__(256) void k_embed(const int* __restrict__ tokens,
                                               const float* __restrict__ emb,
                                               float* __restrict__ x) {
  int idx = blockIdx.x * 256 + threadIdx.x;
  int row = idx / 192, c4 = idx % 192;
  int tok = tokens[row];
  reinterpret_cast<float4*>(x + (size_t)row * DMODEL)[c4] =
      reinterpret_cast<const float4*>(emb + (size_t)tok * DMODEL)[c4];
}

// ---------------- T5 relative position bias LUT: lut[h][rel+511], rel = k - q
__global__ __launch_bounds__(256) void k_biaslut(const float* __restrict__ rel_bias,
                                                 float* __restrict__ lut) {
  int idx = blockIdx.x * 256 + threadIdx.x;   // h*1024 + i
  int h = idx >> 10, i = idx & 1023;
  int rel = i - 511;
  int ret = rel > 0 ? 16 : 0;
  int n = rel < 0 ? -rel : rel;
  int b;
  if (n < 8) {
    b = n;
  } else {
    float r = logf((float)n * 0.125f) / 2.772588722239781f * 8.0f;
    int lg = 8 + (int)r;
    b = lg < 15 ? lg : 15;
  }
  b += ret;
  lut[idx] = rel_bias[b * NHEAD + h];
}

// ---------------- RMSNorm: wave per row, float4 loads, no barrier
template <int BF16OUT>
__global__ __launch_bounds__(256) void k_rmsnorm(const float* __restrict__ x,
                                                 const float* __restrict__ w,
                                                 void* __restrict__ out) {
  int row = blockIdx.x * 4 + (threadIdx.x >> 6);
  int lane = threadIdx.x & 63;
  const float4* xr = reinterpret_cast<const float4*>(x + (size_t)row * DMODEL);
  float4 a = xr[lane], b = xr[lane + 64], c = xr[lane + 128];
  float ss = a.x * a.x + a.y * a.y + a.z * a.z + a.w * a.w
           + b.x * b.x + b.y * b.y + b.z * b.z + b.w * b.w
           + c.x * c.x + c.y * c.y + c.z * c.z + c.w * c.w;
#pragma unroll
  for (int off = 1; off < 64; off <<= 1) ss += __shfl_xor(ss, off);
  float sc = rsqrtf(ss * (1.0f / 768.0f) + 1e-6f);
  const float4* wr = reinterpret_cast<const float4*>(w);
  float4 w0 = wr[lane], w1 = wr[lane + 64], w2 = wr[lane + 128];
  if (BF16OUT) {
    u16x4* o = reinterpret_cast<u16x4*>((u16*)out + (size_t)row * DMODEL);
    u16x4 v0, v1, v2;
    v0[0] = f2bf(a.x * sc * w0.x); v0[1] = f2bf(a.y * sc * w0.y);
    v0[2] = f2bf(a.z * sc * w0.z); v0[3] = f2bf(a.w * sc * w0.w);
    v1[0] = f2bf(b.x * sc * w1.x); v1[1] = f2bf(b.y * sc * w1.y);
    v1[2] = f2bf(b.z * sc * w1.z); v1[3] = f2bf(b.w * sc * w1.w);
    v2[0] = f2bf(c.x * sc * w2.x); v2[1] = f2bf(c.y * sc * w2.y);
    v2[2] = f2bf(c.z * sc * w2.z); v2[3] = f2bf(c.w * sc * w2.w);
    o[lane] = v0; o[lane + 64] = v1; o[lane + 128] = v2;
  } else {
    float4* o = reinterpret_cast<float4*>((float*)out + (size_t)row * DMODEL);
    float4 v0, v1, v2;
    v0.x = a.x * sc * w0.x; v0.y = a.y * sc * w0.y; v0.z = a.z * sc * w0.z; v0.w = a.w * sc * w0.w;
    v1.x = b.x * sc * w1.x; v1.y = b.y * sc * w1.y; v1.z = b.z * sc * w1.z; v1.w = b.w * sc * w1.w;
    v2.x = c.x * sc * w2.x; v2.y = c.y * sc * w2.y; v2.z = c.z * sc * w2.z; v2.w = c.w * sc * w2.w;
    o[lane] = v0; o[lane + 64] = v1; o[lane + 128] = v2;
  }
}

// ---------------- async global->LDS, 16B per lane
__device__ __forceinline__ void gload_lds16(const void* g, void* l) {
  __builtin_amdgcn_global_load_lds((const __attribute__((address_space(1))) void*)g,
                                   (__attribute__((address_space(3))) void*)l, 16, 0, 0);
}

// ---------------- 256x128 8-wave BK=64 triple-buffered pipelined bf16 GEMM: C = A[M,K]*Bt[N,K]^T
// LDS buffer (u16): A [256 rows][64 k] at 0 (16384), B [128 rows][64 k] at 16384 (8192)
//   -> 24576 u16 = 48KB per buffer, 3 buffers = 144KB. Rows are 128B; chunk XOR ^(row&7)
//   (R7-verified conflict-free); source applies the same involution (linear gload dest).
// Pipeline: stage tile t+2 (A 4 issues in p0, B 2 issues in p1); counted vmcnt(6)/tile.
// EPI: 0 = store bf16, 1 = relu -> bf16, 2 = += f32 (residual, single writer)
template <int EPI>
__global__ __launch_bounds__(512, 2) void k_gemm(const u16* __restrict__ A, const u16* __restrict__ Bt,
                                                 u16* __restrict__ outb, float* __restrict__ outf,
                                                 int M, int N, int K) {
  __shared__ u16 lds[3 * 24576];   // 144 KiB
  const int NT = K >> 6;
  int tid = threadIdx.x;
  int lane = tid & 63, wid = tid >> 6;
  int lr = lane & 15, lh = lane >> 4;
  int wm = wid >> 1, wn = wid & 1;   // 4M x 2N waves, 64x64 per wave

  // T1: bijective XCD swizzle, N-FASTEST within chunk (A-panel L2 reuse across bn)
  int gx = gridDim.x, gm = gridDim.y;
  int nwg = gx * gm;
  int linear = blockIdx.y * gx + blockIdx.x;
  int cpx = nwg >> 3;
  int swz = (linear & 7) * cpx + (linear >> 3);
  int bn = (swz % gx) * 128;
  int bm = (swz / gx) * 256;

  const u16* Ab = A  + (size_t)bm * K;
  const u16* Bb = Bt + (size_t)bn * K;

  f32x4 acc[4][4] = {};

  // stage A region of tile kt: 256 rows x 64 k (2048 elems of 16B, 4 issues)
  auto STAGE_A = [&](int kt, u16* buf) {
#pragma unroll
    for (int i = 0; i < 4; i++) {
      int elem = i * 512 + tid;
      int row = elem >> 3, ch = elem & 7;
      int chs = ch ^ (row & 7);
      gload_lds16(Ab + (size_t)row * K + kt * 64 + chs * 8, buf + elem * 8);
    }
  };
  // stage B region: 128 rows x 64 k (1024 elems, 2 issues)
  auto STAGE_B = [&](int kt, u16* buf) {
#pragma unroll
    for (int i = 0; i < 2; i++) {
      int elem = i * 512 + tid;
      int row = elem >> 3, ch = elem & 7;
      int chs = ch ^ (row & 7);
      gload_lds16(Bb + (size_t)row * K + kt * 64 + chs * 8, buf + 16384 + elem * 8);
    }
  };

  // prologue: tiles 0,1 (A0,B0,A1,B1 = 12 issues)
  STAGE_A(0, lds);
  STAGE_B(0, lds);
  STAGE_A(1, lds + 24576);
  STAGE_B(1, lds + 24576);
  asm volatile("s_waitcnt vmcnt(6)" ::: "memory");   // tile0 landed; tile1 (6) in flight
  __builtin_amdgcn_s_barrier();

  bf16x8 af[4], bfr[2][4];

#define DSA(KK)                                                                 \
  _Pragma("unroll") for (int i = 0; i < 4; i++) {                               \
    int r = wm * 64 + i * 16 + lr;                                              \
    af[i] = *reinterpret_cast<const bf16x8*>(cur + r * 64 + ((((KK) * 4 + lh) ^ (r & 7)) * 8)); \
  }
#define MFMA16(KK)                                                              \
  __builtin_amdgcn_s_setprio(1);                                                \
  _Pragma("unroll") for (int i = 0; i < 4; i++)                                 \
  _Pragma("unroll") for (int n = 0; n < 4; n++)                                 \
    acc[i][n] = __builtin_amdgcn_mfma_f32_16x16x32_bf16(af[i], bfr[KK][n], acc[i][n], 0, 0, 0); \
  __builtin_amdgcn_s_setprio(0);
#define BAR_LGKM                                                                \
  __builtin_amdgcn_s_barrier();                                                 \
  asm volatile("s_waitcnt lgkmcnt(0)" ::: "memory");                            \
  __builtin_amdgcn_sched_barrier(0);

  int cs = 0;
  for (int t = 0; t < NT; ++t) {
    const u16* cur = lds + cs * 24576;
    int ds = cs + 2; if (ds >= 3) ds -= 3;
    u16* dst = lds + ds * 24576;
    int t2 = t + 2; if (t2 >= NT) t2 -= NT;   // wrapped dummy keeps vmcnt uniform

    // ---- phase 0: read B (both kk) + A kk0; stage A(t+2)
#pragma unroll
    for (int kk = 0; kk < 2; kk++)
#pragma unroll
      for (int n = 0; n < 4; n++) {
        int r = wn * 64 + n * 16 + lr;
        bfr[kk][n] = *reinterpret_cast<const bf16x8*>(cur + 16384 + r * 64 + (((kk * 4 + lh) ^ (r & 7)) * 8));
      }
    DSA(0)
    STAGE_A(t2, dst);
    BAR_LGKM
    MFMA16(0)
    __builtin_amdgcn_s_barrier();

    // ---- phase 1: read A kk1; stage B(t+2); counted vmcnt (never 0)
    DSA(1)
    STAGE_B(t2, dst);
    BAR_LGKM
    MFMA16(1)
    asm volatile("s_waitcnt vmcnt(6)" ::: "memory");
    __builtin_amdgcn_s_barrier();

    cs += 1; if (cs >= 3) cs -= 3;
  }
#undef DSA
#undef MFMA16
#undef BAR_LGKM

  // epilogue
#pragma unroll
  for (int i = 0; i < 4; i++)
#pragma unroll
    for (int n = 0; n < 4; n++)
#pragma unroll
      for (int r = 0; r < 4; r++) {
        int row = bm + wm * 64 + i * 16 + lh * 4 + r;
        int col = bn + wn * 64 + n * 16 + lr;
        size_t idx = (size_t)row * N + col;
        float v = acc[i][n][r];
        if (EPI == 0)      outb[idx] = f2bf(v);
        else if (EPI == 1) outb[idx] = f2bf(v > 0.f ? v : 0.f);
        else               outf[idx] += v;
      }
}

// ---------------- V transpose per (b,h): qkv V-section [S][64] -> vt[bh][64][S] bf16
__global__ __launch_bounds__(256) void k_vtrans(const u16* __restrict__ qkv, u16* __restrict__ vt) {
  __shared__ u16 t[32][33];
  int bh = blockIdx.z;
  int b = bh / NHEAD, h = bh % NHEAD;
  int d0 = blockIdx.x * 32, s0 = blockIdx.y * 32;
  int tx = threadIdx.x, ty = threadIdx.y;
  const u16* src = qkv + (size_t)(b * SEQ + s0) * QKVN + 2 * DMODEL + h * DHEAD + d0;
#pragma unroll
  for (int i = 0; i < 4; i++)
    t[ty + 8 * i][tx] = src[(size_t)(ty + 8 * i) * QKVN + tx];   // t[s][d]
  __syncthreads();
  u16* dst = vt + ((size_t)bh * DHEAD + d0) * SEQ + s0;
#pragma unroll
  for (int i = 0; i < 4; i++)
    dst[(size_t)(ty + 8 * i) * SEQ + tx] = t[tx][ty + 8 * i];
}

// ---------------- MFMA flash attention: KVBLK=64, dbuf prefetch, counted vmcnt,
// LDS bias LUT, per-lane partial denominator, defer-rescale (THR=8)
__global__ __launch_bounds__(256) void k_attn(const u16* __restrict__ qkv,
                                              const u16* __restrict__ vt,
                                              const float* __restrict__ lutg,
                                              u16* __restrict__ ob) {
  __shared__ __align__(16) float lut[1024];
  __shared__ __align__(16) u16 Ks[2][4096];
  __shared__ __align__(16) u16 Vs[2][4096];
  __shared__ __align__(16) u16 Ps[4][2048];
  int b = blockIdx.x / NHEAD, h = blockIdx.x % NHEAD;
  int qt = blockIdx.y;
  int tid = threadIdx.x;
  int lane = tid & 63, wid = tid >> 6;
  int lr = lane & 15, lh = lane >> 4;
  int q0 = qt * 128 + wid * 32;

  reinterpret_cast<float4*>(lut)[tid] = reinterpret_cast<const float4*>(lutg + h * 1024)[tid];

  bf16x8 aq[2][2];
#pragma unroll
  for (int m = 0; m < 2; m++) {
    const u16* qp = qkv + (size_t)(b * SEQ + q0 + m * 16 + lr) * QKVN + h * DHEAD;
#pragma unroll
    for (int kk = 0; kk < 2; kk++)
      aq[m][kk] = *reinterpret_cast<const bf16x8*>(qp + kk * 32 + lh * 8);
  }

  float mrun[2][4], lpart[2][4];
  f32x4 acc_o[2][4] = {};
#pragma unroll
  for (int m = 0; m < 2; m++)
#pragma unroll
    for (int r = 0; r < 4; r++) { mrun[m][r] = -3.0e38f; lpart[m][r] = 0.f; }

  int srow = tid >> 3, sc8 = tid & 7;
  int scs = (sc8 ^ (srow & 7)) << 3;
  const u16* kbase = qkv + (size_t)(b * SEQ + srow) * QKVN + DMODEL + h * DHEAD + scs;
  const u16* vbase = vt + ((size_t)blockIdx.x * DHEAD + srow) * SEQ + scs;

  auto STAGE = [&](int kt, int bufi) {
    int kv0 = kt << 6;
    gload_lds16(kbase + (size_t)kv0 * QKVN,        &Ks[bufi][tid * 8]);
    gload_lds16(kbase + (size_t)(kv0 + 32) * QKVN, &Ks[bufi][2048 + tid * 8]);
    gload_lds16(vbase + kv0,                       &Vs[bufi][tid * 8]);
    gload_lds16(vbase + 32 * SEQ + kv0,            &Vs[bufi][2048 + tid * 8]);
  };

  STAGE(0, 0);
  asm volatile("s_waitcnt vmcnt(0) lgkmcnt(0)" ::: "memory");
  __builtin_amdgcn_s_barrier();

  int ibase = 511 + lr - q0 - lh * 4;
  u16* pw = Ps[wid];

  for (int kt = 0; kt < 8; kt++) {
    int cb = kt & 1;
    __builtin_amdgcn_s_barrier();
    STAGE((kt + 1) & 7, cb ^ 1);
    asm volatile("s_waitcnt vmcnt(4)" ::: "memory");
    __builtin_amdgcn_s_barrier();

    const u16* KsC = Ks[cb];
    const u16* VsC = Vs[cb];
    int kv0 = kt << 6;

    f32x4 sc[2][4] = {};
#pragma unroll
    for (int kk = 0; kk < 2; kk++) {
      bf16x8 bk[4];
#pragma unroll
      for (int n = 0; n < 4; n++) {
        int row = n * 16 + lr;
        int c = (kk * 4 + lh) ^ (lr & 7);
        bk[n] = *reinterpret_cast<const bf16x8*>(KsC + row * 64 + c * 8);
      }
#pragma unroll
      for (int m = 0; m < 2; m++)
#pragma unroll
        for (int n = 0; n < 4; n++)
          sc[m][n] = __builtin_amdgcn_mfma_f32_16x16x32_bf16(aq[m][kk], bk[n], sc[m][n], 0, 0, 0);
    }

    int pred = 1;
    float vmax[2][4];
#pragma unroll
    for (int m = 0; m < 2; m++)
#pragma unroll
      for (int r = 0; r < 4; r++) {
        int ib = ibase + kv0 - m * 16 - r;
#pragma unroll
        for (int n = 0; n < 4; n++)
          sc[m][n][r] += lut[ib + n * 16];
        float v = fmaxf(fmaxf(sc[m][0][r], sc[m][1][r]), fmaxf(sc[m][2][r], sc[m][3][r]));
        v = fmaxf(v, __shfl_xor(v, 1));
        v = fmaxf(v, __shfl_xor(v, 2));
        v = fmaxf(v, __shfl_xor(v, 4));
        v = fmaxf(v, __shfl_xor(v, 8));
        vmax[m][r] = v;
        pred = pred && (v <= mrun[m][r] + 8.0f);
      }
    if (!__all(pred)) {
#pragma unroll
      for (int m = 0; m < 2; m++)
#pragma unroll
        for (int r = 0; r < 4; r++) {
          float mo = mrun[m][r];
          float mn = fmaxf(mo, vmax[m][r]);
          float corr = __expf(mo - mn);
          mrun[m][r] = mn;
          lpart[m][r] *= corr;
#pragma unroll
          for (int n = 0; n < 4; n++) acc_o[m][n][r] *= corr;
        }
    }
#pragma unroll
    for (int m = 0; m < 2; m++)
#pragma unroll
      for (int r = 0; r < 4; r++) {
        float mm = mrun[m][r];
        int prow = m * 16 + lh * 4 + r;
        int pbse = prow * 64;
        int sw = prow & 7;
        float lp = lpart[m][r];
#pragma unroll
        for (int n = 0; n < 4; n++) {
          float pv = __expf(sc[m][n][r] - mm);
          lp += pv;
          pw[pbse + ((((n << 1) | (lr >> 3)) ^ sw) << 3) + (lr & 7)] = f2bf(pv);
        }
        lpart[m][r] = lp;
      }

    asm volatile("s_waitcnt lgkmcnt(0)" ::: "memory");
    __builtin_amdgcn_sched_barrier(0);
#pragma unroll
    for (int kk = 0; kk < 2; kk++) {
      bf16x8 bvv[4], ap[2];
#pragma unroll
      for (int n = 0; n < 4; n++) {
        int row = n * 16 + lr;
        int c = (kk * 4 + lh) ^ (lr & 7);
        bvv[n] = *reinterpret_cast<const bf16x8*>(VsC + row * 64 + c * 8);
      }
#pragma unroll
      for (int m = 0; m < 2; m++) {
        int row = m * 16 + lr;
        int c = (kk * 4 + lh) ^ (lr & 7);
        ap[m] = *reinterpret_cast<const bf16x8*>(pw + row * 64 + c * 8);
      }
#pragma unroll
      for (int m = 0; m < 2; m++)
#pragma unroll
        for (int n = 0; n < 4; n++)
          acc_o[m][n] = __builtin_amdgcn_mfma_f32_16x16x32_bf16(ap[m], bvv[n], acc_o[m][n], 0, 0, 0);
    }
  }

#pragma unroll
  for (int m = 0; m < 2; m++)
#pragma unroll
    for (int r = 0; r < 4; r++) {
      float l = lpart[m][r];
      l += __shfl_xor(l, 1);
      l += __shfl_xor(l, 2);
      l += __shfl_xor(l, 4);
      l += __shfl_xor(l, 8);
      float inv = 1.f / l;
      size_t orow = (size_t)(b * SEQ + q0 + m * 16 + lh * 4 + r);
#pragma unroll
      for (int n = 0; n < 4; n++)
        ob[orow * DMODEL + h * DHEAD + n * 16 + lr] = f2bf(acc_o[m][n][r] * inv);
    }
}

extern "C" void kernel_launch(void* const* d_in, const int* in_sizes, int n_in,
                              void* d_out, int out_size, void* d_ws, size_t ws_size,
                              hipStream_t stream) {
  const int*   tokens = (const int*)  d_in[0];
  const float* emb    = (const float*)d_in[1];
  const float* relb   = (const float*)d_in[2];
  const float* ln1w   = (const float*)d_in[3];
  const float* wq     = (const float*)d_in[4];
  const float* wk     = (const float*)d_in[5];
  const float* wv     = (const float*)d_in[6];
  const float* wo     = (const float*)d_in[7];
  const float* ln2w   = (const float*)d_in[8];
  const float* w1     = (const float*)d_in[9];
  const float* w2     = (const float*)d_in[10];
  const float* lnfw   = (const float*)d_in[11];
  float* out = (float*)d_out;

  char* p = (char*)d_ws;
  auto carve = [&](size_t bytes) { char* r = p; p += (bytes + 255) & ~(size_t)255; return r; };
  const size_t DD = (size_t)DMODEL * DMODEL, DF = (size_t)DMODEL * FDIM;

  u16*   wqkv_t = (u16*)carve(NLAYER * 3 * DD * 2);
  u16*   wo_t   = (u16*)carve(NLAYER * DD * 2);
  u16*   w1_t   = (u16*)carve(NLAYER * DF * 2);
  u16*   w2_t   = (u16*)carve(NLAYER * DF * 2);
  float* x      = (float*)carve((size_t)NROWS * DMODEL * 4);
  u16*   hbuf   = (u16*)carve((size_t)NROWS * DMODEL * 2);
  u16*   qkvbuf = (u16*)carve((size_t)NROWS * QKVN * 2);
  u16*   abuf   = (u16*)carve((size_t)NROWS * DMODEL * 2);
  u16*   fbuf   = (u16*)carve((size_t)NROWS * FDIM * 2);
  float* lutbuf = (float*)carve((size_t)NHEAD * 1024 * 4);
  u16*   vtbuf  = fbuf;   // overlay: vt dead before ffn1 writes fbuf

  dim3 tb(32, 8);
  k_transpose_cvt<<<dim3(24, 24, NLAYER), tb, 0, stream>>>(wq, wqkv_t,          DMODEL, DMODEL, DD, 3 * DD);
  k_transpose_cvt<<<dim3(24, 24, NLAYER), tb, 0, stream>>>(wk, wqkv_t + DD,     DMODEL, DMODEL, DD, 3 * DD);
  k_transpose_cvt<<<dim3(24, 24, NLAYER), tb, 0, stream>>>(wv, wqkv_t + 2 * DD, DMODEL, DMODEL, DD, 3 * DD);
  k_transpose_cvt<<<dim3(24, 24, NLAYER), tb, 0, stream>>>(wo, wo_t,            DMODEL, DMODEL, DD, DD);
  k_transpose_cvt<<<dim3(96, 24, NLAYER), tb, 0, stream>>>(w1, w1_t,            DMODEL, FDIM,   DF, DF);
  k_transpose_cvt<<<dim3(24, 96, NLAYER), tb, 0, stream>>>(w2, w2_t,            FDIM, DMODEL,   DF, DF);

  k_embed<<<NROWS * 192 / 256, 256, 0, stream>>>(tokens, emb, x);
  k_biaslut<<<48, 256, 0, stream>>>(relb, lutbuf);

  for (int i = 0; i < NLAYER; i++) {
    k_rmsnorm<1><<<NROWS / 4, 256, 0, stream>>>(x, ln1w + i * DMODEL, hbuf);
    k_gemm<0><<<dim3(18, 32), 512, 0, stream>>>(hbuf, wqkv_t + (size_t)i * 3 * DD, qkvbuf, nullptr,
                                                NROWS, QKVN, DMODEL);
    k_vtrans<<<dim3(2, 16, 192), tb, 0, stream>>>(qkvbuf, vtbuf);
    k_attn<<<dim3(192, 4), 256, 0, stream>>>(qkvbuf, vtbuf, lutbuf, abuf);
    k_gemm<2><<<dim3(6, 32),  512, 0, stream>>>(abuf, wo_t + (size_t)i * DD, nullptr, x,
                                                NROWS, DMODEL, DMODEL);
    k_rmsnorm<1><<<NROWS / 4, 256, 0, stream>>>(x, ln2w + i * DMODEL, hbuf);
    k_gemm<1><<<dim3(24, 32), 512, 0, stream>>>(hbuf, w1_t + (size_t)i * DF, fbuf, nullptr,
                                                NROWS, FDIM, DMODEL);
    k_gemm<2><<<dim3(6, 32),  512, 0, stream>>>(fbuf, w2_t + (size_t)i * DF, nullptr, x,
                                                NROWS, DMODEL, FDIM);
  }
  k_rmsnorm<0><<<NROWS / 4, 256, 0, stream>>>(x, lnfw, out);
}

// Round 10
// 3122.264 us; speedup vs baseline: 1.3287x; 1.0483x over previous
//
#include <hip/hip_runtime.h>
#include <hip/hip_bf16.h>

typedef unsigned short u16;
typedef unsigned int   u32;
typedef __attribute__((ext_vector_type(8))) __bf16 bf16x8;
typedef __attribute__((ext_vector_type(4))) float  f32x4;
typedef __attribute__((ext_vector_type(4))) u16    u16x4;

#define SEQ     512
#define DMODEL  768
#define NHEAD   12
#define DHEAD   64
#define FDIM    3072
#define NLAYER  12
#define NROWS   8192   // B*S
#define QKVN    2304   // 3*DMODEL

__device__ __forceinline__ u16 f2bf(float f) {
  union { float f; u32 u; } x; x.f = f;
  u32 r = x.u + 0x7fffu + ((x.u >> 16) & 1u);
  return (u16)(r >> 16);
}

// ---------------- weight convert + transpose: in [K][N] f32 -> out [N][K] bf16 (blockIdx.z = layer)
__global__ __launch_bounds__(256) void k_transpose_cvt(const float* __restrict__ in,
                                                       u16* __restrict__ out, int K, int N,
                                                       size_t istride, size_t ostride) {
  __shared__ float tile[32][33];
  in  += (size_t)blockIdx.z * istride;
  out += (size_t)blockIdx.z * ostride;
  int nb = blockIdx.x * 32, kb = blockIdx.y * 32;
  int tx = threadIdx.x, ty = threadIdx.y;
#pragma unroll
  for (int i = 0; i < 4; i++)
    tile[ty + 8 * i][tx] = in[(size_t)(kb + ty + 8 * i) * N + nb + tx];
  __syncthreads();
#pragma unroll
  for (int i = 0; i < 4; i++)
    out[(size_t)(nb + ty + 8 * i) * K + kb + tx] = f2bf(tile[tx][ty + 8 * i]);
}

// ---------------- embedding gather (f32)
__global__ __launch_bounds__(256) void k_embed(const int* __restrict__ tokens,
                                               const float* __restrict__ emb,
                                               float* __restrict__ x) {
  int idx = blockIdx.x * 256 + threadIdx.x;
  int row = idx / 192, c4 = idx % 192;
  int tok = tokens[row];
  reinterpret_cast<float4*>(x + (size_t)row * DMODEL)[c4] =
      reinterpret_cast<const float4*>(emb + (size_t)tok * DMODEL)[c4];
}

// ---------------- T5 relative position bias LUT: lut[h][rel+511], rel = k - q
__global__ __launch_bounds__(256) void k_biaslut(const float* __restrict__ rel_bias,
                                                 float* __restrict__ lut) {
  int idx = blockIdx.x * 256 + threadIdx.x;   // h*1024 + i
  int h = idx >> 10, i = idx & 1023;
  int rel = i - 511;
  int ret = rel > 0 ? 16 : 0;
  int n = rel < 0 ? -rel : rel;
  int b;
  if (n < 8) {
    b = n;
  } else {
    float r = logf((float)n * 0.125f) / 2.772588722239781f * 8.0f;
    int lg = 8 + (int)r;
    b = lg < 15 ? lg : 15;
  }
  b += ret;
  lut[idx] = rel_bias[b * NHEAD + h];
}

// ---------------- RMSNorm: wave per row, float4 loads, no barrier
template <int BF16OUT>
__global__ __launch_bounds__(256) void k_rmsnorm(const float* __restrict__ x,
                                                 const float* __restrict__ w,
                                                 void* __restrict__ out) {
  int row = blockIdx.x * 4 + (threadIdx.x >> 6);
  int lane = threadIdx.x & 63;
  const float4* xr = reinterpret_cast<const float4*>(x + (size_t)row * DMODEL);
  float4 a = xr[lane], b = xr[lane + 64], c = xr[lane + 128];
  float ss = a.x * a.x + a.y * a.y + a.z * a.z + a.w * a.w
           + b.x * b.x + b.y * b.y + b.z * b.z + b.w * b.w
           + c.x * c.x + c.y * c.y + c.z * c.z + c.w * c.w;
#pragma unroll
  for (int off = 1; off < 64; off <<= 1) ss += __shfl_xor(ss, off);
  float sc = rsqrtf(ss * (1.0f / 768.0f) + 1e-6f);
  const float4* wr = reinterpret_cast<const float4*>(w);
  float4 w0 = wr[lane], w1 = wr[lane + 64], w2 = wr[lane + 128];
  if (BF16OUT) {
    u16x4* o = reinterpret_cast<u16x4*>((u16*)out + (size_t)row * DMODEL);
    u16x4 v0, v1, v2;
    v0[0] = f2bf(a.x * sc * w0.x); v0[1] = f2bf(a.y * sc * w0.y);
    v0[2] = f2bf(a.z * sc * w0.z); v0[3] = f2bf(a.w * sc * w0.w);
    v1[0] = f2bf(b.x * sc * w1.x); v1[1] = f2bf(b.y * sc * w1.y);
    v1[2] = f2bf(b.z * sc * w1.z); v1[3] = f2bf(b.w * sc * w1.w);
    v2[0] = f2bf(c.x * sc * w2.x); v2[1] = f2bf(c.y * sc * w2.y);
    v2[2] = f2bf(c.z * sc * w2.z); v2[3] = f2bf(c.w * sc * w2.w);
    o[lane] = v0; o[lane + 64] = v1; o[lane + 128] = v2;
  } else {
    float4* o = reinterpret_cast<float4*>((float*)out + (size_t)row * DMODEL);
    float4 v0, v1, v2;
    v0.x = a.x * sc * w0.x; v0.y = a.y * sc * w0.y; v0.z = a.z * sc * w0.z; v0.w = a.w * sc * w0.w;
    v1.x = b.x * sc * w1.x; v1.y = b.y * sc * w1.y; v1.z = b.z * sc * w1.z; v1.w = b.w * sc * w1.w;
    v2.x = c.x * sc * w2.x; v2.y = c.y * sc * w2.y; v2.z = c.z * sc * w2.z; v2.w = c.w * sc * w2.w;
    o[lane] = v0; o[lane + 64] = v1; o[lane + 128] = v2;
  }
}

// ---------------- async global->LDS, 16B per lane
__device__ __forceinline__ void gload_lds16(const void* g, void* l) {
  __builtin_amdgcn_global_load_lds((const __attribute__((address_space(1))) void*)g,
                                   (__attribute__((address_space(3))) void*)l, 16, 0, 0);
}

// ---------------- 256x(NF*32) 8-wave BK=64 triple-buffered pipelined bf16 GEMM.
// C[M,N] = A[M,K] * Bt[N,K]^T. 8 waves = 4M x 2N; per-wave 64 x NF*16.
// LDS buffer (u16): A [256 rows][64 k] at 0 (16384), B [<=128 rows][64 k] at 16384 (8192)
//   -> 24576 u16 = 48KB per buffer x 3. Rows 128B; chunk XOR ^(row&7) (R9-verified 0-conflict);
//   source applies the same involution (linear gload dest). NF=3: B rows 96 real, stage rows
//   clamped to 95 for elems >= 768 (dup into padding, never read) -> uniform vmcnt.
// Pipeline: stage tile t+2 (A 4 issues p0, B 2 issues p1); counted vmcnt(6)/tile (never 0).
// EPI: 0 = store bf16, 1 = relu -> bf16, 2 = += f32 (residual, single writer)
template <int EPI, int NF>
__global__ __launch_bounds__(512, 2) void k_gemm(const u16* __restrict__ A, const u16* __restrict__ Bt,
                                                 u16* __restrict__ outb, float* __restrict__ outf,
                                                 int M, int N, int K) {
  __shared__ u16 lds[3 * 24576];   // 144 KiB
  const int NT = K >> 6;
  const int BROWS = 2 * NF * 16;   // real B rows per tile
  int tid = threadIdx.x;
  int lane = tid & 63, wid = tid >> 6;
  int lr = lane & 15, lh = lane >> 4;
  int wm = wid >> 1, wn = wid & 1;   // 4M x 2N waves

  // T1: bijective XCD swizzle, N-FASTEST within chunk (A-panel L2 reuse across bn)
  int gx = gridDim.x, gm = gridDim.y;
  int nwg = gx * gm;
  int linear = blockIdx.y * gx + blockIdx.x;
  int cpx = nwg >> 3;
  int swz = (linear & 7) * cpx + (linear >> 3);
  int bn = (swz % gx) * BROWS;
  int bm = (swz / gx) * 256;

  const u16* Ab = A  + (size_t)bm * K;
  const u16* Bb = Bt + (size_t)bn * K;

  f32x4 acc[4][NF] = {};

  auto STAGE_A = [&](int kt, u16* buf) {
#pragma unroll
    for (int i = 0; i < 4; i++) {
      int elem = i * 512 + tid;
      int row = elem >> 3, ch = elem & 7;
      int chs = ch ^ (row & 7);
      gload_lds16(Ab + (size_t)row * K + kt * 64 + chs * 8, buf + elem * 8);
    }
  };
  auto STAGE_B = [&](int kt, u16* buf) {
#pragma unroll
    for (int i = 0; i < 2; i++) {
      int elem = i * 512 + tid;
      int row = elem >> 3, ch = elem & 7;
      if (row >= BROWS) row = BROWS - 1;   // dup into padding (NF=3 only), keeps vmcnt uniform
      int chs = ch ^ (row & 7);
      gload_lds16(Bb + (size_t)row * K + kt * 64 + chs * 8, buf + 16384 + elem * 8);
    }
  };

  // prologue: tiles 0,1 (A0,B0,A1,B1 = 12 issues)
  STAGE_A(0, lds);
  STAGE_B(0, lds);
  STAGE_A(1, lds + 24576);
  STAGE_B(1, lds + 24576);
  asm volatile("s_waitcnt vmcnt(6)" ::: "memory");   // tile0 landed; tile1 (6) in flight
  __builtin_amdgcn_s_barrier();

  bf16x8 af[4], bfr[2][NF];

#define DSA(KK)                                                                 \
  _Pragma("unroll") for (int i = 0; i < 4; i++) {                               \
    int r = wm * 64 + i * 16 + lr;                                              \
    af[i] = *reinterpret_cast<const bf16x8*>(cur + r * 64 + ((((KK) * 4 + lh) ^ (r & 7)) * 8)); \
  }
#define MFMA_G(KK)                                                              \
  __builtin_amdgcn_s_setprio(1);                                                \
  _Pragma("unroll") for (int i = 0; i < 4; i++)                                 \
  _Pragma("unroll") for (int n = 0; n < NF; n++)                                \
    acc[i][n] = __builtin_amdgcn_mfma_f32_16x16x32_bf16(af[i], bfr[KK][n], acc[i][n], 0, 0, 0); \
  __builtin_amdgcn_s_setprio(0);
#define BAR_LGKM                                                                \
  __builtin_amdgcn_s_barrier();                                                 \
  asm volatile("s_waitcnt lgkmcnt(0)" ::: "memory");                            \
  __builtin_amdgcn_sched_barrier(0);

  int cs = 0;
  for (int t = 0; t < NT; ++t) {
    const u16* cur = lds + cs * 24576;
    int ds = cs + 2; if (ds >= 3) ds -= 3;
    u16* dst = lds + ds * 24576;
    int t2 = t + 2; if (t2 >= NT) t2 -= NT;   // wrapped dummy keeps vmcnt uniform

    // ---- phase 0: read B (both kk) + A kk0; stage A(t+2)
#pragma unroll
    for (int kk = 0; kk < 2; kk++)
#pragma unroll
      for (int n = 0; n < NF; n++) {
        int r = wn * (NF * 16) + n * 16 + lr;
        bfr[kk][n] = *reinterpret_cast<const bf16x8*>(cur + 16384 + r * 64 + (((kk * 4 + lh) ^ (r & 7)) * 8));
      }
    DSA(0)
    STAGE_A(t2, dst);
    BAR_LGKM
    MFMA_G(0)
    __builtin_amdgcn_s_barrier();

    // ---- phase 1: read A kk1; stage B(t+2); counted vmcnt (never 0)
    DSA(1)
    STAGE_B(t2, dst);
    BAR_LGKM
    MFMA_G(1)
    asm volatile("s_waitcnt vmcnt(6)" ::: "memory");
    __builtin_amdgcn_s_barrier();

    cs += 1; if (cs >= 3) cs -= 3;
  }
#undef DSA
#undef MFMA_G
#undef BAR_LGKM

  // epilogue
#pragma unroll
  for (int i = 0; i < 4; i++)
#pragma unroll
    for (int n = 0; n < NF; n++)
#pragma unroll
      for (int r = 0; r < 4; r++) {
        int row = bm + wm * 64 + i * 16 + lh * 4 + r;
        int col = bn + wn * (NF * 16) + n * 16 + lr;
        size_t idx = (size_t)row * N + col;
        float v = acc[i][n][r];
        if (EPI == 0)      outb[idx] = f2bf(v);
        else if (EPI == 1) outb[idx] = f2bf(v > 0.f ? v : 0.f);
        else               outf[idx] += v;
      }
}

// ---------------- V transpose per (b,h): qkv V-section [S][64] -> vt[bh][64][S] bf16
__global__ __launch_bounds__(256) void k_vtrans(const u16* __restrict__ qkv, u16* __restrict__ vt) {
  __shared__ u16 t[32][33];
  int bh = blockIdx.z;
  int b = bh / NHEAD, h = bh % NHEAD;
  int d0 = blockIdx.x * 32, s0 = blockIdx.y * 32;
  int tx = threadIdx.x, ty = threadIdx.y;
  const u16* src = qkv + (size_t)(b * SEQ + s0) * QKVN + 2 * DMODEL + h * DHEAD + d0;
#pragma unroll
  for (int i = 0; i < 4; i++)
    t[ty + 8 * i][tx] = src[(size_t)(ty + 8 * i) * QKVN + tx];   // t[s][d]
  __syncthreads();
  u16* dst = vt + ((size_t)bh * DHEAD + d0) * SEQ + s0;
#pragma unroll
  for (int i = 0; i < 4; i++)
    dst[(size_t)(ty + 8 * i) * SEQ + tx] = t[tx][ty + 8 * i];
}

// ---------------- MFMA flash attention: KVBLK=64, dbuf prefetch, counted vmcnt,
// LDS bias LUT, per-lane partial denominator, defer-rescale (THR=8)
__global__ __launch_bounds__(256) void k_attn(const u16* __restrict__ qkv,
                                              const u16* __restrict__ vt,
                                              const float* __restrict__ lutg,
                                              u16* __restrict__ ob) {
  __shared__ __align__(16) float lut[1024];
  __shared__ __align__(16) u16 Ks[2][4096];
  __shared__ __align__(16) u16 Vs[2][4096];
  __shared__ __align__(16) u16 Ps[4][2048];
  int b = blockIdx.x / NHEAD, h = blockIdx.x % NHEAD;
  int qt = blockIdx.y;
  int tid = threadIdx.x;
  int lane = tid & 63, wid = tid >> 6;
  int lr = lane & 15, lh = lane >> 4;
  int q0 = qt * 128 + wid * 32;

  reinterpret_cast<float4*>(lut)[tid] = reinterpret_cast<const float4*>(lutg + h * 1024)[tid];

  bf16x8 aq[2][2];
#pragma unroll
  for (int m = 0; m < 2; m++) {
    const u16* qp = qkv + (size_t)(b * SEQ + q0 + m * 16 + lr) * QKVN + h * DHEAD;
#pragma unroll
    for (int kk = 0; kk < 2; kk++)
      aq[m][kk] = *reinterpret_cast<const bf16x8*>(qp + kk * 32 + lh * 8);
  }

  float mrun[2][4], lpart[2][4];
  f32x4 acc_o[2][4] = {};
#pragma unroll
  for (int m = 0; m < 2; m++)
#pragma unroll
    for (int r = 0; r < 4; r++) { mrun[m][r] = -3.0e38f; lpart[m][r] = 0.f; }

  int srow = tid >> 3, sc8 = tid & 7;
  int scs = (sc8 ^ (srow & 7)) << 3;
  const u16* kbase = qkv + (size_t)(b * SEQ + srow) * QKVN + DMODEL + h * DHEAD + scs;
  const u16* vbase = vt + ((size_t)blockIdx.x * DHEAD + srow) * SEQ + scs;

  auto STAGE = [&](int kt, int bufi) {
    int kv0 = kt << 6;
    gload_lds16(kbase + (size_t)kv0 * QKVN,        &Ks[bufi][tid * 8]);
    gload_lds16(kbase + (size_t)(kv0 + 32) * QKVN, &Ks[bufi][2048 + tid * 8]);
    gload_lds16(vbase + kv0,                       &Vs[bufi][tid * 8]);
    gload_lds16(vbase + 32 * SEQ + kv0,            &Vs[bufi][2048 + tid * 8]);
  };

  STAGE(0, 0);
  asm volatile("s_waitcnt vmcnt(0) lgkmcnt(0)" ::: "memory");
  __builtin_amdgcn_s_barrier();

  int ibase = 511 + lr - q0 - lh * 4;
  u16* pw = Ps[wid];

  for (int kt = 0; kt < 8; kt++) {
    int cb = kt & 1;
    __builtin_amdgcn_s_barrier();
    STAGE((kt + 1) & 7, cb ^ 1);
    asm volatile("s_waitcnt vmcnt(4)" ::: "memory");
    __builtin_amdgcn_s_barrier();

    const u16* KsC = Ks[cb];
    const u16* VsC = Vs[cb];
    int kv0 = kt << 6;

    f32x4 sc[2][4] = {};
#pragma unroll
    for (int kk = 0; kk < 2; kk++) {
      bf16x8 bk[4];
#pragma unroll
      for (int n = 0; n < 4; n++) {
        int row = n * 16 + lr;
        int c = (kk * 4 + lh) ^ (lr & 7);
        bk[n] = *reinterpret_cast<const bf16x8*>(KsC + row * 64 + c * 8);
      }
#pragma unroll
      for (int m = 0; m < 2; m++)
#pragma unroll
        for (int n = 0; n < 4; n++)
          sc[m][n] = __builtin_amdgcn_mfma_f32_16x16x32_bf16(aq[m][kk], bk[n], sc[m][n], 0, 0, 0);
    }

    int pred = 1;
    float vmax[2][4];
#pragma unroll
    for (int m = 0; m < 2; m++)
#pragma unroll
      for (int r = 0; r < 4; r++) {
        int ib = ibase + kv0 - m * 16 - r;
#pragma unroll
        for (int n = 0; n < 4; n++)
          sc[m][n][r] += lut[ib + n * 16];
        float v = fmaxf(fmaxf(sc[m][0][r], sc[m][1][r]), fmaxf(sc[m][2][r], sc[m][3][r]));
        v = fmaxf(v, __shfl_xor(v, 1));
        v = fmaxf(v, __shfl_xor(v, 2));
        v = fmaxf(v, __shfl_xor(v, 4));
        v = fmaxf(v, __shfl_xor(v, 8));
        vmax[m][r] = v;
        pred = pred && (v <= mrun[m][r] + 8.0f);
      }
    if (!__all(pred)) {
#pragma unroll
      for (int m = 0; m < 2; m++)
#pragma unroll
        for (int r = 0; r < 4; r++) {
          float mo = mrun[m][r];
          float mn = fmaxf(mo, vmax[m][r]);
          float corr = __expf(mo - mn);
          mrun[m][r] = mn;
          lpart[m][r] *= corr;
#pragma unroll
          for (int n = 0; n < 4; n++) acc_o[m][n][r] *= corr;
        }
    }
#pragma unroll
    for (int m = 0; m < 2; m++)
#pragma unroll
      for (int r = 0; r < 4; r++) {
        float mm = mrun[m][r];
        int prow = m * 16 + lh * 4 + r;
        int pbse = prow * 64;
        int sw = prow & 7;
        float lp = lpart[m][r];
#pragma unroll
        for (int n = 0; n < 4; n++) {
          float pv = __expf(sc[m][n][r] - mm);
          lp += pv;
          pw[pbse + ((((n << 1) | (lr >> 3)) ^ sw) << 3) + (lr & 7)] = f2bf(pv);
        }
        lpart[m][r] = lp;
      }

    asm volatile("s_waitcnt lgkmcnt(0)" ::: "memory");
    __builtin_amdgcn_sched_barrier(0);
#pragma unroll
    for (int kk = 0; kk < 2; kk++) {
      bf16x8 bvv[4], ap[2];
#pragma unroll
      for (int n = 0; n < 4; n++) {
        int row = n * 16 + lr;
        int c = (kk * 4 + lh) ^ (lr & 7);
        bvv[n] = *reinterpret_cast<const bf16x8*>(VsC + row * 64 + c * 8);
      }
#pragma unroll
      for (int m = 0; m < 2; m++) {
        int row = m * 16 + lr;
        int c = (kk * 4 + lh) ^ (lr & 7);
        ap[m] = *reinterpret_cast<const bf16x8*>(pw + row * 64 + c * 8);
      }
#pragma unroll
      for (int m = 0; m < 2; m++)
#pragma unroll
        for (int n = 0; n < 4; n++)
          acc_o[m][n] = __builtin_amdgcn_mfma_f32_16x16x32_bf16(ap[m], bvv[n], acc_o[m][n], 0, 0, 0);
    }
  }

#pragma unroll
  for (int m = 0; m < 2; m++)
#pragma unroll
    for (int r = 0; r < 4; r++) {
      float l = lpart[m][r];
      l += __shfl_xor(l, 1);
      l += __shfl_xor(l, 2);
      l += __shfl_xor(l, 4);
      l += __shfl_xor(l, 8);
      float inv = 1.f / l;
      size_t orow = (size_t)(b * SEQ + q0 + m * 16 + lh * 4 + r);
#pragma unroll
      for (int n = 0; n < 4; n++)
        ob[orow * DMODEL + h * DHEAD + n * 16 + lr] = f2bf(acc_o[m][n][r] * inv);
    }
}

extern "C" void kernel_launch(void* const* d_in, const int* in_sizes, int n_in,
                              void* d_out, int out_size, void* d_ws, size_t ws_size,
                              hipStream_t stream) {
  const int*   tokens = (const int*)  d_in[0];
  const float* emb    = (const float*)d_in[1];
  const float* relb   = (const float*)d_in[2];
  const float* ln1w   = (const float*)d_in[3];
  const float* wq     = (const float*)d_in[4];
  const float* wk     = (const float*)d_in[5];
  const float* wv     = (const float*)d_in[6];
  const float* wo     = (const float*)d_in[7];
  const float* ln2w   = (const float*)d_in[8];
  const float* w1     = (const float*)d_in[9];
  const float* w2     = (const float*)d_in[10];
  const float* lnfw   = (const float*)d_in[11];
  float* out = (float*)d_out;

  char* p = (char*)d_ws;
  auto carve = [&](size_t bytes) { char* r = p; p += (bytes + 255) & ~(size_t)255; return r; };
  const size_t DD = (size_t)DMODEL * DMODEL, DF = (size_t)DMODEL * FDIM;

  u16*   wqkv_t = (u16*)carve(NLAYER * 3 * DD * 2);
  u16*   wo_t   = (u16*)carve(NLAYER * DD * 2);
  u16*   w1_t   = (u16*)carve(NLAYER * DF * 2);
  u16*   w2_t   = (u16*)carve(NLAYER * DF * 2);
  float* x      = (float*)carve((size_t)NROWS * DMODEL * 4);
  u16*   hbuf   = (u16*)carve((size_t)NROWS * DMODEL * 2);
  u16*   qkvbuf = (u16*)carve((size_t)NROWS * QKVN * 2);
  u16*   abuf   = (u16*)carve((size_t)NROWS * DMODEL * 2);
  u16*   fbuf   = (u16*)carve((size_t)NROWS * FDIM * 2);
  float* lutbuf = (float*)carve((size_t)NHEAD * 1024 * 4);
  u16*   vtbuf  = fbuf;   // overlay: vt dead before ffn1 writes fbuf

  dim3 tb(32, 8);
  k_transpose_cvt<<<dim3(24, 24, NLAYER), tb, 0, stream>>>(wq, wqkv_t,          DMODEL, DMODEL, DD, 3 * DD);
  k_transpose_cvt<<<dim3(24, 24, NLAYER), tb, 0, stream>>>(wk, wqkv_t + DD,     DMODEL, DMODEL, DD, 3 * DD);
  k_transpose_cvt<<<dim3(24, 24, NLAYER), tb, 0, stream>>>(wv, wqkv_t + 2 * DD, DMODEL, DMODEL, DD, 3 * DD);
  k_transpose_cvt<<<dim3(24, 24, NLAYER), tb, 0, stream>>>(wo, wo_t,            DMODEL, DMODEL, DD, DD);
  k_transpose_cvt<<<dim3(96, 24, NLAYER), tb, 0, stream>>>(w1, w1_t,            DMODEL, FDIM,   DF, DF);
  k_transpose_cvt<<<dim3(24, 96, NLAYER), tb, 0, stream>>>(w2, w2_t,            FDIM, DMODEL,   DF, DF);

  k_embed<<<NROWS * 192 / 256, 256, 0, stream>>>(tokens, emb, x);
  k_biaslut<<<48, 256, 0, stream>>>(relb, lutbuf);

  for (int i = 0; i < NLAYER; i++) {
    k_rmsnorm<1><<<NROWS / 4, 256, 0, stream>>>(x, ln1w + i * DMODEL, hbuf);
    // QKV: NF=3 -> N-tile 96, grid (24,32)=768 blocks (3 exact rounds, 100% fill)
    k_gemm<0, 3><<<dim3(24, 32), 512, 0, stream>>>(hbuf, wqkv_t + (size_t)i * 3 * DD, qkvbuf, nullptr,
                                                   NROWS, QKVN, DMODEL);
    k_vtrans<<<dim3(2, 16, 192), tb, 0, stream>>>(qkvbuf, vtbuf);
    k_attn<<<dim3(192, 4), 256, 0, stream>>>(qkvbuf, vtbuf, lutbuf, abuf);
    // WO: NF=3 -> grid (8,32)=256 blocks (exactly 1 round)
    k_gemm<2, 3><<<dim3(8, 32),  512, 0, stream>>>(abuf, wo_t + (size_t)i * DD, nullptr, x,
                                                   NROWS, DMODEL, DMODEL);
    k_rmsnorm<1><<<NROWS / 4, 256, 0, stream>>>(x, ln2w + i * DMODEL, hbuf);
    // FFN1: NF=4 -> grid (24,32)=768 blocks (3 exact rounds)
    k_gemm<1, 4><<<dim3(24, 32), 512, 0, stream>>>(hbuf, w1_t + (size_t)i * DF, fbuf, nullptr,
                                                   NROWS, FDIM, DMODEL);
    // FFN2: NF=3 -> grid (8,32)=256 blocks (exactly 1 round)
    k_gemm<2, 3><<<dim3(8, 32),  512, 0, stream>>>(fbuf, w2_t + (size_t)i * DF, nullptr, x,
                                                   NROWS, DMODEL, FDIM);
  }
  k_rmsnorm<0><<<NROWS / 4, 256, 0, stream>>>(x, lnfw, out);
}